// Round 11
// baseline (1214.953 us; speedup 1.0000x reference)
//
#include <hip/hip_runtime.h>

#define B 4
#define CIN 256
#define T 8192
#define NL 24
#define SH 0.70710678118654752f
#define SKIP_SCALE 0.20412414523193150f  // (1/24)^0.5

typedef unsigned short u16;
typedef __attribute__((ext_vector_type(4))) float f32x4;
typedef __attribute__((ext_vector_type(8))) short s16x8;
typedef __attribute__((ext_vector_type(4))) short s16x4;

__device__ inline u16 f2bf(float f) {            // RNE float->bf16
  unsigned u = __float_as_uint(f);
  return (u16)((u + 0x7fffu + ((u >> 16) & 1u)) >> 16);
}
__device__ inline float bf2f(u16 h) { return __uint_as_float((unsigned)h << 16); }
__device__ inline float gate_fn(float a, float g) {
  float e2 = __expf(-2.f * fabsf(a));
  float th = (1.f - e2) * __builtin_amdgcn_rcpf(1.f + e2);
  float sg = __builtin_amdgcn_rcpf(1.f + __expf(-g));
  return copysignf(th, a) * sg;
}

// ---------------- weight prep (merged) ----------------
__global__ void cvt_all(const float* __restrict__ conv_w, const float* __restrict__ skip_w,
                        const float* __restrict__ out_w, const float* __restrict__ first_w,
                        const float* __restrict__ last1_w, const float* __restrict__ last2_w,
                        u16* __restrict__ wcv, u16* __restrict__ wso, u16* __restrict__ wf,
                        u16* __restrict__ w1, u16* __restrict__ w2) {
  int i = blockIdx.x * 256 + threadIdx.x;
  if (i < 2359296) {  // conv: dst [l][k][o][c] <- src [l][o][c][k]
    int c = i & 127, o = (i >> 7) & 255, kk = (i >> 15) % 3, l = (i >> 15) / 3;
    wcv[i] = f2bf(conv_w[(((size_t)l * 256 + o) * 128 + c) * 3 + kk]);
    return;
  }
  i -= 2359296;
  if (i < 786432) {
    int c = i & 127, r = (i >> 7) & 255, l = i >> 15;
    float v = (r < 128) ? skip_w[((size_t)l * 128 + r) * 128 + c]
                        : out_w[((size_t)l * 128 + (r - 128)) * 128 + c];
    wso[i] = f2bf(v);
    return;
  }
  i -= 786432;
  if (i < 32768) { wf[i] = f2bf(first_w[i]); return; }
  i -= 32768;
  if (i < 16384) { w1[i] = f2bf(last1_w[i]); return; }
  i -= 16384;
  if (i < 32768) { w2[i] = f2bf(last2_w[i]); return; }
}
__global__ void sumsb_kernel(const float* __restrict__ sb, float* __restrict__ dst) {
  int c = threadIdx.x;  // 128
  float s = 0.f;
  for (int l = 0; l < NL; l++) s += sb[l * 128 + c];
  dst[c] = s;
}

// ---------------- first 1x1 conv: hf = first_w @ x + first_b (fp32 out) ----------------
__global__ __launch_bounds__(256, 2)
void first_kernel(const float* __restrict__ x, const u16* __restrict__ wf,
                  const float* __restrict__ fb, float* __restrict__ hf) {
  __shared__ u16 xT[64 * 256];
  const int tid = threadIdx.x, wv = tid >> 6, lane = tid & 63, lo = lane & 15, hi = lane >> 4;
  const int t0 = blockIdx.x * 64, b = blockIdx.y;
  #pragma unroll
  for (int it = 0; it < 16; it++) {
    int idx = tid + it * 256;
    int c = idx >> 4, t4 = (idx & 15) << 2;
    f32x4 v = *(const f32x4*)(x + ((size_t)b * CIN + c) * T + t0 + t4);
    #pragma unroll
    for (int i = 0; i < 4; i++) {
      int t = t4 + i;
      *(u16*)((char*)xT + t * 512 + ((c * 2) ^ ((t & 7) << 4))) = f2bf(v[i]);
    }
  }
  __syncthreads();
  f32x4 acc[2][4];
  #pragma unroll
  for (int m = 0; m < 2; m++)
    #pragma unroll
    for (int n = 0; n < 4; n++) acc[m][n] = (f32x4){0.f, 0.f, 0.f, 0.f};
  #pragma unroll
  for (int s = 0; s < 8; s++) {
    s16x8 af[2], bf[4];
    #pragma unroll
    for (int m = 0; m < 2; m++)
      af[m] = *(const s16x8*)(wf + (size_t)(wv * 32 + m * 16 + lo) * CIN + s * 32 + hi * 8);
    #pragma unroll
    for (int n = 0; n < 4; n++) {
      int t = n * 16 + lo;
      bf[n] = *(const s16x8*)((const char*)xT + t * 512 + ((s * 64 + hi * 16) ^ ((t & 7) << 4)));
    }
    #pragma unroll
    for (int m = 0; m < 2; m++)
      #pragma unroll
      for (int n = 0; n < 4; n++)
        acc[m][n] = __builtin_amdgcn_mfma_f32_16x16x32_bf16(af[m], bf[n], acc[m][n], 0, 0, 0);
  }
  #pragma unroll
  for (int m = 0; m < 2; m++) {
    int c0 = wv * 32 + m * 16 + hi * 4;
    f32x4 bv = *(const f32x4*)(fb + c0);
    #pragma unroll
    for (int n = 0; n < 4; n++) {
      int t = n * 16 + lo;
      *(f32x4*)(hf + ((size_t)b * T + t0 + t) * 128 + c0) = acc[m][n] + bv;
    }
  }
}

// ==================== PRIMARY: 6-layer group, 64-col own tile ====================
// 512 blocks x 512 thr, LDS 80KB -> 2 blocks/CU. Block owns (b, 64-t tile).
// hHI rows r in [0,192) <-> t = t0-128+r (own = rows [128,192)); hLO own rows only.
// Validity frontier: need_0=0, need_{j+1}=need_j+2^{j+1} -> 2,6,14,30,62,126<=128.
// Per layer: 64-col chunks right-to-left (in-place safe), cmin={0,0,0,0,1,2}.
// Redundant chunks: ALL 8 waves run the out-GEMM (16 rows each). Own chunk:
// waves 0-3 skip-GEMM (acc in VGPRs all 6 layers), waves 4-7 out-GEMM.
__global__ __launch_bounds__(512, 4)
void group6_kernel(const float* __restrict__ hf_in, float* __restrict__ hf_out,
                   float* __restrict__ skip,
                   const u16* __restrict__ wcv_g, const float* __restrict__ cb_g,
                   const u16* __restrict__ wso_g, const float* __restrict__ ob_g,
                   int first) {
  extern __shared__ char smem[];
  u16* hHI = (u16*)smem;                 // 192 rows x 256B = 48KB
  u16* hLO = (u16*)(smem + 49152);       // 64 rows x 256B = 16KB (own rows r-128)
  u16* zh  = (u16*)(smem + 65536);       // 64 rows x 256B = 16KB
  const int tid = threadIdx.x, wv = tid >> 6, lane = tid & 63, lo = lane & 15, hi = lane >> 4;
  const int tj = blockIdx.x, b = blockIdx.y, t0 = tj * 64;

  // ---- stage 192 rows: fp32 -> hi plane (all) + lo plane (own rows) ----
  #pragma unroll
  for (int it = 0; it < 12; it++) {
    int p = tid + it * 512;                      // 6144 f32x4
    int r = p >> 5, cq = p & 31;
    int t = t0 - 128 + r;
    f32x4 v = (f32x4){0.f, 0.f, 0.f, 0.f};
    if (t >= 0) v = *(const f32x4*)(hf_in + ((size_t)b * T + t) * 128 + cq * 4);
    s16x4 phi, plo;
    #pragma unroll
    for (int q = 0; q < 4; q++) {
      u16 hb = f2bf(v[q]);
      phi[q] = (short)hb;
      plo[q] = (short)f2bf(v[q] - bf2f(hb));
    }
    int key = (cq * 8) ^ ((r & 7) << 4);
    *(s16x4*)((char*)hHI + r * 256 + key) = phi;
    if (r >= 128) *(s16x4*)((char*)hLO + (r - 128) * 256 + key) = plo;
  }
  __syncthreads();

  f32x4 sk[2][4];   // skip accumulator (waves 0-3 only), own 64 cols
  #pragma unroll
  for (int m = 0; m < 2; m++)
    #pragma unroll
    for (int n = 0; n < 4; n++) sk[m][n] = (f32x4){0.f, 0.f, 0.f, 0.f};

  #pragma unroll 1
  for (int j = 0; j < 6; j++) {
    const int d = 1 << j;
    const u16* wc = wcv_g + (size_t)j * 3 * 256 * 128;
    const float* cb = cb_g + j * 256;
    const u16* wsl = wso_g + (size_t)j * 256 * 128;
    const float* ob = ob_g + j * 128;
    const int cmin = (j == 5) ? 2 : (j == 4) ? 1 : 0;

    #pragma unroll 1
    for (int ci = 0; ci < 3; ci++) {
      const int c = 2 - ci;            // right-to-left chunks
      if (c < cmin) continue;

      // ---- conv GEMM (a+g): all 8 waves, N = 64 cols ----
      f32x4 acc[2][4];
      #pragma unroll
      for (int m = 0; m < 2; m++)
        #pragma unroll
        for (int n = 0; n < 4; n++) acc[m][n] = (f32x4){0.f, 0.f, 0.f, 0.f};
      const int oa = wv * 16, og = 128 + wv * 16;
      #pragma unroll
      for (int k = 0; k < 3; k++) {
        const int rb = 64 * c - (2 - k) * d + lo;
        #pragma unroll
        for (int s = 0; s < 4; s++) {
          s16x8 af0 = *(const s16x8*)(wc + (size_t)(k * 256 + oa + lo) * 128 + s * 32 + hi * 8);
          s16x8 af1 = *(const s16x8*)(wc + (size_t)(k * 256 + og + lo) * 128 + s * 32 + hi * 8);
          const int cbyte = s * 64 + hi * 16;
          s16x8 bfr[4];
          #pragma unroll
          for (int n = 0; n < 4; n++) {
            int rr = rb + n * 16;
            if (rr < 0) rr = 0;        // clamped; outputs below the need-frontier are discarded
            bfr[n] = *(const s16x8*)((const char*)hHI + rr * 256 + (cbyte ^ ((rr & 7) << 4)));
          }
          #pragma unroll
          for (int n = 0; n < 4; n++) {
            acc[0][n] = __builtin_amdgcn_mfma_f32_16x16x32_bf16(af0, bfr[n], acc[0][n], 0, 0, 0);
            acc[1][n] = __builtin_amdgcn_mfma_f32_16x16x32_bf16(af1, bfr[n], acc[1][n], 0, 0, 0);
          }
        }
      }
      // ---- gate -> zh ----
      {
        f32x4 ba = *(const f32x4*)(cb + oa + hi * 4);
        f32x4 bg = *(const f32x4*)(cb + og + hi * 4);
        #pragma unroll
        for (int n = 0; n < 4; n++) {
          int u = n * 16 + lo;
          s16x4 pk;
          #pragma unroll
          for (int q = 0; q < 4; q++)
            pk[q] = (short)f2bf(gate_fn(acc[0][n][q] + ba[q], acc[1][n][q] + bg[q]));
          *(s16x4*)((char*)zh + u * 256 + (((oa + hi * 4) * 2) ^ ((u & 7) << 4))) = pk;
        }
      }
      __syncthreads();   // zh ready; all conv h-reads done before in-place writes

      if (c == 2) {
        // ---- own chunk: waves 0-3 skip-GEMM into sk; waves 4-7 out-GEMM + h update ----
        if (wv < 4) {
          const int ro = wv * 32;
          #pragma unroll
          for (int s = 0; s < 4; s++) {
            s16x8 af0 = *(const s16x8*)(wsl + (size_t)(ro + lo) * 128 + s * 32 + hi * 8);
            s16x8 af1 = *(const s16x8*)(wsl + (size_t)(ro + 16 + lo) * 128 + s * 32 + hi * 8);
            const int cbyte = s * 64 + hi * 16;
            s16x8 bfr[4];
            #pragma unroll
            for (int n = 0; n < 4; n++) {
              int u = n * 16 + lo;
              bfr[n] = *(const s16x8*)((const char*)zh + u * 256 + (cbyte ^ ((u & 7) << 4)));
            }
            #pragma unroll
            for (int n = 0; n < 4; n++) {
              sk[0][n] = __builtin_amdgcn_mfma_f32_16x16x32_bf16(af0, bfr[n], sk[0][n], 0, 0, 0);
              sk[1][n] = __builtin_amdgcn_mfma_f32_16x16x32_bf16(af1, bfr[n], sk[1][n], 0, 0, 0);
            }
          }
        } else {
          const int ro = (wv - 4) * 32;
          f32x4 a2[2][4];
          #pragma unroll
          for (int m = 0; m < 2; m++)
            #pragma unroll
            for (int n = 0; n < 4; n++) a2[m][n] = (f32x4){0.f, 0.f, 0.f, 0.f};
          #pragma unroll
          for (int s = 0; s < 4; s++) {
            s16x8 af0 = *(const s16x8*)(wsl + (size_t)(128 + ro + lo) * 128 + s * 32 + hi * 8);
            s16x8 af1 = *(const s16x8*)(wsl + (size_t)(128 + ro + 16 + lo) * 128 + s * 32 + hi * 8);
            const int cbyte = s * 64 + hi * 16;
            s16x8 bfr[4];
            #pragma unroll
            for (int n = 0; n < 4; n++) {
              int u = n * 16 + lo;
              bfr[n] = *(const s16x8*)((const char*)zh + u * 256 + (cbyte ^ ((u & 7) << 4)));
            }
            #pragma unroll
            for (int n = 0; n < 4; n++) {
              a2[0][n] = __builtin_amdgcn_mfma_f32_16x16x32_bf16(af0, bfr[n], a2[0][n], 0, 0, 0);
              a2[1][n] = __builtin_amdgcn_mfma_f32_16x16x32_bf16(af1, bfr[n], a2[1][n], 0, 0, 0);
            }
          }
          #pragma unroll
          for (int m = 0; m < 2; m++) {
            int c0 = ro + m * 16 + hi * 4;
            f32x4 ob4 = *(const f32x4*)(ob + c0);
            #pragma unroll
            for (int n = 0; n < 4; n++) {
              int u = n * 16 + lo;
              int r = 128 + u;
              int key = (c0 * 2) ^ ((r & 7) << 4);
              s16x4 vhi = *(const s16x4*)((const char*)hHI + r * 256 + key);
              s16x4 vlo = *(const s16x4*)((const char*)hLO + u * 256 + key);
              f32x4 hold;
              #pragma unroll
              for (int q = 0; q < 4; q++)
                hold[q] = bf2f((u16)vhi[q]) + bf2f((u16)vlo[q]);
              f32x4 hnew = (a2[m][n] + ob4 + hold) * SH;
              if (j == 5) {
                *(f32x4*)(hf_out + ((size_t)b * T + t0 + u) * 128 + c0) = hnew;
              } else {
                s16x4 nhi, nlo;
                #pragma unroll
                for (int q = 0; q < 4; q++) {
                  u16 hb = f2bf(hnew[q]);
                  nhi[q] = (short)hb;
                  nlo[q] = (short)f2bf(hnew[q] - bf2f(hb));
                }
                *(s16x4*)((char*)hHI + r * 256 + key) = nhi;
                *(s16x4*)((char*)hLO + u * 256 + key) = nlo;
              }
            }
          }
        }
      } else {
        // ---- redundant chunk: ALL 8 waves out-GEMM (16 rows each) + hi-only h update ----
        const int ro = wv * 16;
        f32x4 a1[4];
        #pragma unroll
        for (int n = 0; n < 4; n++) a1[n] = (f32x4){0.f, 0.f, 0.f, 0.f};
        #pragma unroll
        for (int s = 0; s < 4; s++) {
          s16x8 af0 = *(const s16x8*)(wsl + (size_t)(128 + ro + lo) * 128 + s * 32 + hi * 8);
          const int cbyte = s * 64 + hi * 16;
          s16x8 bfr[4];
          #pragma unroll
          for (int n = 0; n < 4; n++) {
            int u = n * 16 + lo;
            bfr[n] = *(const s16x8*)((const char*)zh + u * 256 + (cbyte ^ ((u & 7) << 4)));
          }
          #pragma unroll
          for (int n = 0; n < 4; n++)
            a1[n] = __builtin_amdgcn_mfma_f32_16x16x32_bf16(af0, bfr[n], a1[n], 0, 0, 0);
        }
        {
          int c0 = ro + hi * 4;
          f32x4 ob4 = *(const f32x4*)(ob + c0);
          #pragma unroll
          for (int n = 0; n < 4; n++) {
            int u = n * 16 + lo;
            int r = 64 * c + u;
            int key = (c0 * 2) ^ ((r & 7) << 4);
            s16x4 vhi = *(const s16x4*)((const char*)hHI + r * 256 + key);
            f32x4 hold;
            #pragma unroll
            for (int q = 0; q < 4; q++) hold[q] = bf2f((u16)vhi[q]);
            f32x4 hnew = (a1[n] + ob4 + hold) * SH;
            s16x4 nhi;
            #pragma unroll
            for (int q = 0; q < 4; q++) nhi[q] = (short)f2bf(hnew[q]);
            *(s16x4*)((char*)hHI + r * 256 + key) = nhi;
          }
        }
      }
      __syncthreads();   // h updates visible before next chunk/layer conv
    }
  }

  // ---- skip writeback: one RMW per group ----
  if (wv < 4) {
    #pragma unroll
    for (int m = 0; m < 2; m++) {
      int c0 = wv * 32 + m * 16 + hi * 4;
      #pragma unroll
      for (int n = 0; n < 4; n++) {
        int t = t0 + n * 16 + lo;
        size_t off = ((size_t)b * T + t) * 128 + c0;
        f32x4 r = sk[m][n];
        if (!first) r += *(const f32x4*)(skip + off);
        *(f32x4*)(skip + off) = r;
      }
    }
  }
}

// ==================== FALLBACK: R7 pair-kernel path (known-good, 697us) ====================
__global__ __launch_bounds__(512, 4)
void pair_kernel(const float* __restrict__ hf_in, float* __restrict__ hf_out,
                 float* __restrict__ skip,
                 const u16* __restrict__ wc1, const float* __restrict__ cb1,
                 const u16* __restrict__ ws1, const float* __restrict__ ob1,
                 const u16* __restrict__ wc2, const float* __restrict__ cb2,
                 const u16* __restrict__ ws2, const float* __restrict__ ob2,
                 int d1, int d2, int first) {
  extern __shared__ u16 lds[];
  u16* h_s = lds;
  u16* zh  = lds + 160 * 128;
  const int tid = threadIdx.x, wv = tid >> 6, lane = tid & 63, lo = lane & 15, hi = lane >> 4;
  const int tj = blockIdx.x, b = blockIdx.y, t0 = tj * 64;
  const int R0 = 128 + 2 * d1;

  for (int p = tid; p < R0 * 32; p += 512) {
    int j0 = p >> 5, cq = p & 31;
    int t = t0 - 64 - 2 * d1 + j0;
    f32x4 v = (f32x4){0.f, 0.f, 0.f, 0.f};
    if (t >= 0) v = *(const f32x4*)(hf_in + ((size_t)b * T + t) * 128 + cq * 4);
    s16x4 pk;
    #pragma unroll
    for (int j = 0; j < 4; j++) pk[j] = (short)f2bf(v[j]);
    *(s16x4*)((char*)h_s + j0 * 256 + ((cq * 8) ^ (((j0 + 64 - 2 * d1) & 7) << 4))) = pk;
  }
  __syncthreads();

  f32x4 A[2][8];
  const int oa = wv * 16, og = 128 + wv * 16;

  #pragma unroll
  for (int m = 0; m < 2; m++)
    #pragma unroll
    for (int n = 0; n < 8; n++) A[m][n] = (f32x4){0.f, 0.f, 0.f, 0.f};
  #pragma unroll
  for (int k = 0; k < 3; k++) {
    const int st = ((lo + (k + 6) * d1) & 7) << 4;
    const int jb = k * d1;
    #pragma unroll
    for (int s = 0; s < 4; s++) {
      s16x8 af0 = *(const s16x8*)(wc1 + ((size_t)(k * 256 + oa + lo)) * 128 + s * 32 + hi * 8);
      s16x8 af1 = *(const s16x8*)(wc1 + ((size_t)(k * 256 + og + lo)) * 128 + s * 32 + hi * 8);
      const int cb_ = s * 64 + hi * 16;
      #pragma unroll
      for (int h2 = 0; h2 < 2; h2++) {
        s16x8 bf[4];
        #pragma unroll
        for (int nn = 0; nn < 4; nn++) {
          int j0 = (h2 * 4 + nn) * 16 + lo + jb;
          bf[nn] = *(const s16x8*)((const char*)h_s + j0 * 256 + (cb_ ^ st));
        }
        #pragma unroll
        for (int nn = 0; nn < 4; nn++) {
          A[0][h2 * 4 + nn] = __builtin_amdgcn_mfma_f32_16x16x32_bf16(af0, bf[nn], A[0][h2 * 4 + nn], 0, 0, 0);
          A[1][h2 * 4 + nn] = __builtin_amdgcn_mfma_f32_16x16x32_bf16(af1, bf[nn], A[1][h2 * 4 + nn], 0, 0, 0);
        }
      }
    }
  }
  {
    f32x4 ba = *(const f32x4*)(cb1 + oa + hi * 4);
    f32x4 bg = *(const f32x4*)(cb1 + og + hi * 4);
    #pragma unroll
    for (int n = 0; n < 8; n++) {
      int u = n * 16 + lo;
      s16x4 pk;
      #pragma unroll
      for (int j = 0; j < 4; j++)
        pk[j] = (short)f2bf(gate_fn(A[0][n][j] + ba[j], A[1][n][j] + bg[j]));
      *(s16x4*)((char*)zh + u * 256 + (((oa + hi * 4) * 2) ^ ((lo & 7) << 4))) = pk;
    }
  }
  __syncthreads();

  const int ro = wv * 32;
  if (wv < 4) {
    #pragma unroll
    for (int m = 0; m < 2; m++)
      #pragma unroll
      for (int nn = 0; nn < 4; nn++) A[m][nn + 4] = (f32x4){0.f, 0.f, 0.f, 0.f};
    #pragma unroll
    for (int s = 0; s < 4; s++) {
      s16x8 af0 = *(const s16x8*)(ws1 + (size_t)(ro + lo) * 128 + s * 32 + hi * 8);
      s16x8 af1 = *(const s16x8*)(ws1 + (size_t)(ro + 16 + lo) * 128 + s * 32 + hi * 8);
      const int cb_ = s * 64 + hi * 16;
      s16x8 bf[4];
      #pragma unroll
      for (int nn = 0; nn < 4; nn++) {
        int u = (nn + 4) * 16 + lo;
        bf[nn] = *(const s16x8*)((const char*)zh + u * 256 + (cb_ ^ ((lo & 7) << 4)));
      }
      #pragma unroll
      for (int nn = 0; nn < 4; nn++) {
        A[0][nn + 4] = __builtin_amdgcn_mfma_f32_16x16x32_bf16(af0, bf[nn], A[0][nn + 4], 0, 0, 0);
        A[1][nn + 4] = __builtin_amdgcn_mfma_f32_16x16x32_bf16(af1, bf[nn], A[1][nn + 4], 0, 0, 0);
      }
    }
  } else {
    #pragma unroll
    for (int m = 0; m < 2; m++)
      #pragma unroll
      for (int n = 0; n < 8; n++) A[m][n] = (f32x4){0.f, 0.f, 0.f, 0.f};
    #pragma unroll
    for (int s = 0; s < 4; s++) {
      s16x8 af0 = *(const s16x8*)(ws1 + (size_t)(ro + lo) * 128 + s * 32 + hi * 8);
      s16x8 af1 = *(const s16x8*)(ws1 + (size_t)(ro + 16 + lo) * 128 + s * 32 + hi * 8);
      const int cb_ = s * 64 + hi * 16;
      #pragma unroll
      for (int h2 = 0; h2 < 2; h2++) {
        s16x8 bf[4];
        #pragma unroll
        for (int nn = 0; nn < 4; nn++) {
          int u = (h2 * 4 + nn) * 16 + lo;
          bf[nn] = *(const s16x8*)((const char*)zh + u * 256 + (cb_ ^ ((lo & 7) << 4)));
        }
        #pragma unroll
        for (int nn = 0; nn < 4; nn++) {
          A[0][h2 * 4 + nn] = __builtin_amdgcn_mfma_f32_16x16x32_bf16(af0, bf[nn], A[0][h2 * 4 + nn], 0, 0, 0);
          A[1][h2 * 4 + nn] = __builtin_amdgcn_mfma_f32_16x16x32_bf16(af1, bf[nn], A[1][h2 * 4 + nn], 0, 0, 0);
        }
      }
    }
    #pragma unroll
    for (int m = 0; m < 2; m++) {
      int c0 = (wv - 4) * 32 + m * 16 + hi * 4;
      f32x4 ob4 = *(const f32x4*)(ob1 + c0);
      #pragma unroll
      for (int n = 0; n < 8; n++) {
        int u = n * 16 + lo;
        int t_out = t0 - 64 + u;
        f32x4 h0 = (f32x4){0.f, 0.f, 0.f, 0.f};
        if (t_out >= 0) h0 = *(const f32x4*)(hf_in + ((size_t)b * T + t_out) * 128 + c0);
        f32x4 h1 = (A[m][n] + ob4 + h0) * SH;
        if (t_out < 0) h1 = (f32x4){0.f, 0.f, 0.f, 0.f};
        A[m][n] = h1;
        s16x4 pk;
        #pragma unroll
        for (int j = 0; j < 4; j++) pk[j] = (short)f2bf(h1[j]);
        *(s16x4*)((char*)h_s + u * 256 + ((c0 * 2) ^ ((lo & 7) << 4))) = pk;
      }
    }
  }
  __syncthreads();

  #pragma unroll
  for (int m = 0; m < 2; m++)
    #pragma unroll
    for (int n = 0; n < 4; n++) A[m][n] = (f32x4){0.f, 0.f, 0.f, 0.f};
  #pragma unroll
  for (int k = 0; k < 3; k++) {
    const int st = ((lo + (k + 6) * d2) & 7) << 4;
    const int jb2 = 64 - 2 * d2 + k * d2;
    #pragma unroll
    for (int s = 0; s < 4; s++) {
      s16x8 af0 = *(const s16x8*)(wc2 + ((size_t)(k * 256 + oa + lo)) * 128 + s * 32 + hi * 8);
      s16x8 af1 = *(const s16x8*)(wc2 + ((size_t)(k * 256 + og + lo)) * 128 + s * 32 + hi * 8);
      const int cb_ = s * 64 + hi * 16;
      s16x8 bf[4];
      #pragma unroll
      for (int nn = 0; nn < 4; nn++) {
        int j1 = nn * 16 + lo + jb2;
        bf[nn] = *(const s16x8*)((const char*)h_s + j1 * 256 + (cb_ ^ st));
      }
      #pragma unroll
      for (int nn = 0; nn < 4; nn++) {
        A[0][nn] = __builtin_amdgcn_mfma_f32_16x16x32_bf16(af0, bf[nn], A[0][nn], 0, 0, 0);
        A[1][nn] = __builtin_amdgcn_mfma_f32_16x16x32_bf16(af1, bf[nn], A[1][nn], 0, 0, 0);
      }
    }
  }
  {
    f32x4 ba = *(const f32x4*)(cb2 + oa + hi * 4);
    f32x4 bg = *(const f32x4*)(cb2 + og + hi * 4);
    #pragma unroll
    for (int n = 0; n < 4; n++) {
      int u = n * 16 + lo;
      s16x4 pk;
      #pragma unroll
      for (int j = 0; j < 4; j++)
        pk[j] = (short)f2bf(gate_fn(A[0][n][j] + ba[j], A[1][n][j] + bg[j]));
      *(s16x4*)((char*)zh + u * 256 + (((oa + hi * 4) * 2) ^ ((lo & 7) << 4))) = pk;
    }
  }
  __syncthreads();

  if (wv < 4) {
    #pragma unroll
    for (int s = 0; s < 4; s++) {
      s16x8 af0 = *(const s16x8*)(ws2 + (size_t)(ro + lo) * 128 + s * 32 + hi * 8);
      s16x8 af1 = *(const s16x8*)(ws2 + (size_t)(ro + 16 + lo) * 128 + s * 32 + hi * 8);
      const int cb_ = s * 64 + hi * 16;
      s16x8 bf[4];
      #pragma unroll
      for (int nn = 0; nn < 4; nn++) {
        int u = nn * 16 + lo;
        bf[nn] = *(const s16x8*)((const char*)zh + u * 256 + (cb_ ^ ((lo & 7) << 4)));
      }
      #pragma unroll
      for (int nn = 0; nn < 4; nn++) {
        A[0][nn + 4] = __builtin_amdgcn_mfma_f32_16x16x32_bf16(af0, bf[nn], A[0][nn + 4], 0, 0, 0);
        A[1][nn + 4] = __builtin_amdgcn_mfma_f32_16x16x32_bf16(af1, bf[nn], A[1][nn + 4], 0, 0, 0);
      }
    }
    #pragma unroll
    for (int m = 0; m < 2; m++) {
      int c0 = ro + m * 16 + hi * 4;
      #pragma unroll
      for (int n = 0; n < 4; n++) {
        int t = t0 + n * 16 + lo;
        size_t off = ((size_t)b * T + t) * 128 + c0;
        f32x4 r = A[m][n + 4];
        if (!first) r += *(const f32x4*)(skip + off);
        *(f32x4*)(skip + off) = r;
      }
    }
  } else {
    #pragma unroll
    for (int m = 0; m < 2; m++)
      #pragma unroll
      for (int n = 0; n < 4; n++) A[m][n] = (f32x4){0.f, 0.f, 0.f, 0.f};
    #pragma unroll
    for (int s = 0; s < 4; s++) {
      s16x8 af0 = *(const s16x8*)(ws2 + (size_t)(ro + lo) * 128 + s * 32 + hi * 8);
      s16x8 af1 = *(const s16x8*)(ws2 + (size_t)(ro + 16 + lo) * 128 + s * 32 + hi * 8);
      const int cb_ = s * 64 + hi * 16;
      s16x8 bf[4];
      #pragma unroll
      for (int nn = 0; nn < 4; nn++) {
        int u = nn * 16 + lo;
        bf[nn] = *(const s16x8*)((const char*)zh + u * 256 + (cb_ ^ ((lo & 7) << 4)));
      }
      #pragma unroll
      for (int nn = 0; nn < 4; nn++) {
        A[0][nn] = __builtin_amdgcn_mfma_f32_16x16x32_bf16(af0, bf[nn], A[0][nn], 0, 0, 0);
        A[1][nn] = __builtin_amdgcn_mfma_f32_16x16x32_bf16(af1, bf[nn], A[1][nn], 0, 0, 0);
      }
    }
    #pragma unroll
    for (int m = 0; m < 2; m++) {
      int c0 = (wv - 4) * 32 + m * 16 + hi * 4;
      f32x4 ob4 = *(const f32x4*)(ob2 + c0);
      #pragma unroll
      for (int n = 0; n < 4; n++) {
        int t = t0 + n * 16 + lo;
        f32x4 h2v = (A[m][n] + ob4 + A[m][n + 4]) * SH;
        *(f32x4*)(hf_out + ((size_t)b * T + t) * 128 + c0) = h2v;
      }
    }
  }
}

// ---------------- fused head ----------------
__global__ __launch_bounds__(256, 2)
void head_kernel(const float* __restrict__ skip, const float* __restrict__ sumsb,
                 const u16* __restrict__ w1, const float* __restrict__ b1v,
                 const u16* __restrict__ w2, const float* __restrict__ b2v,
                 float* __restrict__ out) {
  __shared__ u16 sT[64 * 128];
  __shared__ u16 s1T[64 * 128];
  const int tid = threadIdx.x, wv = tid >> 6, lane = tid & 63, lo = lane & 15, hi = lane >> 4;
  const int t0 = blockIdx.x * 64, b = blockIdx.y;

  #pragma unroll
  for (int it = 0; it < 8; it++) {
    int p = tid + it * 256;
    int t = p >> 5, cq = p & 31;
    f32x4 v = *(const f32x4*)(skip + ((size_t)b * T + t0 + t) * 128 + cq * 4);
    f32x4 sb4 = *(const f32x4*)(sumsb + cq * 4);
    s16x4 pk;
    #pragma unroll
    for (int j = 0; j < 4; j++) pk[j] = (short)f2bf(fmaxf((v[j] + sb4[j]) * SKIP_SCALE, 0.f));
    *(s16x4*)((char*)sT + t * 256 + ((cq * 8) ^ ((t & 7) << 4))) = pk;
  }
  __syncthreads();
  {
    f32x4 acc[2][4];
    #pragma unroll
    for (int m = 0; m < 2; m++)
      #pragma unroll
      for (int n = 0; n < 4; n++) acc[m][n] = (f32x4){0.f, 0.f, 0.f, 0.f};
    #pragma unroll
    for (int s = 0; s < 4; s++) {
      s16x8 af0 = *(const s16x8*)(w1 + (size_t)(wv * 32 + lo) * 128 + s * 32 + hi * 8);
      s16x8 af1 = *(const s16x8*)(w1 + (size_t)(wv * 32 + 16 + lo) * 128 + s * 32 + hi * 8);
      #pragma unroll
      for (int n = 0; n < 4; n++) {
        int t = n * 16 + lo;
        s16x8 bf = *(const s16x8*)((const char*)sT + t * 256 + ((s * 64 + hi * 16) ^ ((t & 7) << 4)));
        acc[0][n] = __builtin_amdgcn_mfma_f32_16x16x32_bf16(af0, bf, acc[0][n], 0, 0, 0);
        acc[1][n] = __builtin_amdgcn_mfma_f32_16x16x32_bf16(af1, bf, acc[1][n], 0, 0, 0);
      }
    }
    #pragma unroll
    for (int m = 0; m < 2; m++) {
      int c0 = wv * 32 + m * 16 + hi * 4;
      f32x4 bv = *(const f32x4*)(b1v + c0);
      #pragma unroll
      for (int n = 0; n < 4; n++) {
        int t = n * 16 + lo;
        s16x4 pk;
        #pragma unroll
        for (int j = 0; j < 4; j++) pk[j] = (short)f2bf(fmaxf(acc[m][n][j] + bv[j], 0.f));
        *(s16x4*)((char*)s1T + t * 256 + ((c0 * 2) ^ ((t & 7) << 4))) = pk;
      }
    }
  }
  __syncthreads();
  {
    f32x4 acc[4][4];
    #pragma unroll
    for (int m = 0; m < 4; m++)
      #pragma unroll
      for (int n = 0; n < 4; n++) acc[m][n] = (f32x4){0.f, 0.f, 0.f, 0.f};
    #pragma unroll
    for (int s = 0; s < 4; s++) {
      s16x8 af[4];
      #pragma unroll
      for (int m = 0; m < 4; m++)
        af[m] = *(const s16x8*)(w2 + (size_t)(wv * 64 + m * 16 + lo) * 128 + s * 32 + hi * 8);
      #pragma unroll
      for (int n = 0; n < 4; n++) {
        int t = n * 16 + lo;
        s16x8 bf = *(const s16x8*)((const char*)s1T + t * 256 + ((s * 64 + hi * 16) ^ ((t & 7) << 4)));
        #pragma unroll
        for (int m = 0; m < 4; m++)
          acc[m][n] = __builtin_amdgcn_mfma_f32_16x16x32_bf16(af[m], bf, acc[m][n], 0, 0, 0);
      }
    }
    #pragma unroll
    for (int m = 0; m < 4; m++) {
      int c0 = wv * 64 + m * 16 + hi * 4;
      f32x4 bv = *(const f32x4*)(b2v + c0);
      #pragma unroll
      for (int n = 0; n < 4; n++) {
        int t = t0 + n * 16 + lo;
        f32x4 r = acc[m][n] + bv;
        #pragma unroll
        for (int j = 0; j < 4; j++) out[((size_t)b * CIN + c0 + j) * T + t] = r[j];
      }
    }
  }
}

// ---------------------------------------------------------------------------
extern "C" void kernel_launch(void* const* d_in, const int* in_sizes, int n_in,
                              void* d_out, int out_size, void* d_ws, size_t ws_size,
                              hipStream_t stream) {
  const float* x       = (const float*)d_in[0];
  const float* first_w = (const float*)d_in[1];
  const float* first_b = (const float*)d_in[2];
  const float* conv_w  = (const float*)d_in[3];
  const float* conv_b  = (const float*)d_in[4];
  const float* out_w   = (const float*)d_in[5];
  const float* out_b   = (const float*)d_in[6];
  const float* skip_w  = (const float*)d_in[7];
  const float* skip_b  = (const float*)d_in[8];
  const float* last1_w = (const float*)d_in[9];
  const float* last1_b = (const float*)d_in[10];
  const float* last2_w = (const float*)d_in[11];
  const float* last2_b = (const float*)d_in[12];
  float* outp = (float*)d_out;

  u16* wcv = (u16*)d_ws;
  u16* wso = wcv + (size_t)NL * 3 * 256 * 128;
  u16* wfB = wso + (size_t)NL * 256 * 128;
  u16* w1B = wfB + 128 * 256;
  u16* w2B = w1B + 128 * 128;
  float* sumsb = (float*)(w2B + 256 * 128);
  float* skipF = sumsb + 128;                    // 16MB fp32 skip accumulator
  float* hfA = (float*)d_out;                    // residual double-buffer in d_out
  float* hfB = hfA + (size_t)B * T * 128;

  cvt_all<<<12608, 256, 0, stream>>>(conv_w, skip_w, out_w, first_w, last1_w, last2_w,
                                     wcv, wso, wfB, w1B, w2B);
  sumsb_kernel<<<1, 128, 0, stream>>>(skip_b, sumsb);

  dim3 g64(T / 64, B);
  first_kernel<<<g64, 256, 0, stream>>>(x, wfB, first_b, hfA);

  (void)hipFuncSetAttribute((const void*)group6_kernel,
                            hipFuncAttributeMaxDynamicSharedMemorySize, 81920);
  (void)hipGetLastError();

  group6_kernel<<<g64, 512, 81920, stream>>>(hfA, hfB, skipF, wcv, conv_b, wso, out_b, 1);
  hipError_t ce = hipGetLastError();

  if (ce == hipSuccess) {
    for (int g = 1; g < 4; g++) {
      const float* hin = (g & 1) ? hfB : hfA;
      float* hout = (g & 1) ? hfA : hfB;
      group6_kernel<<<g64, 512, 81920, stream>>>(
          hin, hout, skipF,
          wcv + (size_t)g * 6 * 3 * 256 * 128, conv_b + (size_t)g * 6 * 256,
          wso + (size_t)g * 6 * 256 * 128, out_b + (size_t)g * 6 * 128, 0);
    }
  } else {
    // fallback: known-good pair chain (hfA already populated by first_kernel)
    for (int p = 0; p < NL / 2; p++) {
      int l1 = 2 * p, l2 = 2 * p + 1;
      int d1 = 1 << (l1 % 6), d2 = 1 << (l2 % 6);
      const float* hin = (p & 1) ? hfB : hfA;
      float* hout = (p & 1) ? hfA : hfB;
      pair_kernel<<<g64, 512, 73728, stream>>>(
          hin, hout, skipF,
          wcv + (size_t)l1 * 3 * 256 * 128, conv_b + (size_t)l1 * 256,
          wso + (size_t)l1 * 256 * 128, out_b + (size_t)l1 * 128,
          wcv + (size_t)l2 * 3 * 256 * 128, conv_b + (size_t)l2 * 256,
          wso + (size_t)l2 * 256 * 128, out_b + (size_t)l2 * 128,
          d1, d2, p == 0 ? 1 : 0);
    }
  }
  head_kernel<<<g64, 256, 0, stream>>>(skipF, sumsb, w1B, last1_b, w2B, last2_b, outp);
}

// Round 12
// 1214.489 us; speedup vs baseline: 1.0004x; 1.0004x over previous
//
#include <hip/hip_runtime.h>

#define B 4
#define CIN 256
#define T 8192
#define NL 24
#define SH 0.70710678118654752f
#define SKIP_SCALE 0.20412414523193150f  // (1/24)^0.5

typedef unsigned short u16;
typedef __attribute__((ext_vector_type(4))) float f32x4;
typedef __attribute__((ext_vector_type(8))) short s16x8;
typedef __attribute__((ext_vector_type(4))) short s16x4;

__device__ inline u16 f2bf(float f) {            // RNE float->bf16
  unsigned u = __float_as_uint(f);
  return (u16)((u + 0x7fffu + ((u >> 16) & 1u)) >> 16);
}
__device__ inline float bf2f(u16 h) { return __uint_as_float((unsigned)h << 16); }
__device__ inline float gate_fn(float a, float g) {
  float e2 = __expf(-2.f * fabsf(a));
  float th = (1.f - e2) * __builtin_amdgcn_rcpf(1.f + e2);
  float sg = __builtin_amdgcn_rcpf(1.f + __expf(-g));
  return copysignf(th, a) * sg;
}

// ---------------- weight prep (merged) ----------------
__global__ void cvt_all(const float* __restrict__ conv_w, const float* __restrict__ skip_w,
                        const float* __restrict__ out_w, const float* __restrict__ first_w,
                        const float* __restrict__ last1_w, const float* __restrict__ last2_w,
                        u16* __restrict__ wcv, u16* __restrict__ wso, u16* __restrict__ wf,
                        u16* __restrict__ w1, u16* __restrict__ w2) {
  int i = blockIdx.x * 256 + threadIdx.x;
  if (i < 2359296) {  // conv: dst [l][k][o][c] <- src [l][o][c][k]
    int c = i & 127, o = (i >> 7) & 255, kk = (i >> 15) % 3, l = (i >> 15) / 3;
    wcv[i] = f2bf(conv_w[(((size_t)l * 256 + o) * 128 + c) * 3 + kk]);
    return;
  }
  i -= 2359296;
  if (i < 786432) {
    int c = i & 127, r = (i >> 7) & 255, l = i >> 15;
    float v = (r < 128) ? skip_w[((size_t)l * 128 + r) * 128 + c]
                        : out_w[((size_t)l * 128 + (r - 128)) * 128 + c];
    wso[i] = f2bf(v);
    return;
  }
  i -= 786432;
  if (i < 32768) { wf[i] = f2bf(first_w[i]); return; }
  i -= 32768;
  if (i < 16384) { w1[i] = f2bf(last1_w[i]); return; }
  i -= 16384;
  if (i < 32768) { w2[i] = f2bf(last2_w[i]); return; }
}
__global__ void sumsb_kernel(const float* __restrict__ sb, float* __restrict__ dst) {
  int c = threadIdx.x;  // 128
  float s = 0.f;
  for (int l = 0; l < NL; l++) s += sb[l * 128 + c];
  dst[c] = s;
}

// ---------------- first 1x1 conv: hf = first_w @ x + first_b (fp32 out) ----------------
__global__ __launch_bounds__(256, 2)
void first_kernel(const float* __restrict__ x, const u16* __restrict__ wf,
                  const float* __restrict__ fb, float* __restrict__ hf) {
  __shared__ u16 xT[64 * 256];
  const int tid = threadIdx.x, wv = tid >> 6, lane = tid & 63, lo = lane & 15, hi = lane >> 4;
  const int t0 = blockIdx.x * 64, b = blockIdx.y;
  #pragma unroll
  for (int it = 0; it < 16; it++) {
    int idx = tid + it * 256;
    int c = idx >> 4, t4 = (idx & 15) << 2;
    f32x4 v = *(const f32x4*)(x + ((size_t)b * CIN + c) * T + t0 + t4);
    #pragma unroll
    for (int i = 0; i < 4; i++) {
      int t = t4 + i;
      *(u16*)((char*)xT + t * 512 + ((c * 2) ^ ((t & 7) << 4))) = f2bf(v[i]);
    }
  }
  __syncthreads();
  f32x4 acc[2][4];
  #pragma unroll
  for (int m = 0; m < 2; m++)
    #pragma unroll
    for (int n = 0; n < 4; n++) acc[m][n] = (f32x4){0.f, 0.f, 0.f, 0.f};
  #pragma unroll
  for (int s = 0; s < 8; s++) {
    s16x8 af[2], bf[4];
    #pragma unroll
    for (int m = 0; m < 2; m++)
      af[m] = *(const s16x8*)(wf + (size_t)(wv * 32 + m * 16 + lo) * CIN + s * 32 + hi * 8);
    #pragma unroll
    for (int n = 0; n < 4; n++) {
      int t = n * 16 + lo;
      bf[n] = *(const s16x8*)((const char*)xT + t * 512 + ((s * 64 + hi * 16) ^ ((t & 7) << 4)));
    }
    #pragma unroll
    for (int m = 0; m < 2; m++)
      #pragma unroll
      for (int n = 0; n < 4; n++)
        acc[m][n] = __builtin_amdgcn_mfma_f32_16x16x32_bf16(af[m], bf[n], acc[m][n], 0, 0, 0);
  }
  #pragma unroll
  for (int m = 0; m < 2; m++) {
    int c0 = wv * 32 + m * 16 + hi * 4;
    f32x4 bv = *(const f32x4*)(fb + c0);
    #pragma unroll
    for (int n = 0; n < 4; n++) {
      int t = n * 16 + lo;
      *(f32x4*)(hf + ((size_t)b * T + t0 + t) * 128 + c0) = acc[m][n] + bv;
    }
  }
}

// ==================== PRIMARY: 6-layer group, 64-col own tile ====================
// 512 blocks x 512 thr, LDS 80KB -> 2 blocks/CU. Block owns (b, 64-t tile).
// Register budget (launch_bounds(512,4) => 64 arch VGPR + 64 AGPR):
//   sk[2][4] = 32 AGPR (live whole kernel) + acc[2][4] = 32 AGPR (reused for
//   EVERY post-gate GEMM) = 64 peak. R11 spilled (sk+acc+a2 = 96 -> 260MB
//   scratch traffic/dispatch); this version reuses acc and must not spill.
// hHI rows r in [0,192) <-> t = t0-128+r (own = rows [128,192)); hLO own rows.
// Frontier: need_j = 2,6,14,30,62,126 <= 128. Chunks right-to-left, in-place.
__global__ __launch_bounds__(512, 4)
void group6_kernel(const float* __restrict__ hf_in, float* __restrict__ hf_out,
                   float* __restrict__ skip,
                   const u16* __restrict__ wcv_g, const float* __restrict__ cb_g,
                   const u16* __restrict__ wso_g, const float* __restrict__ ob_g,
                   int first) {
  extern __shared__ char smem[];
  u16* hHI = (u16*)smem;                 // 192 rows x 256B = 48KB
  u16* hLO = (u16*)(smem + 49152);       // 64 rows x 256B = 16KB (own rows r-128)
  u16* zh  = (u16*)(smem + 65536);       // 64 rows x 256B = 16KB
  const int tid = threadIdx.x, wv = tid >> 6, lane = tid & 63, lo = lane & 15, hi = lane >> 4;
  const int tj = blockIdx.x, b = blockIdx.y, t0 = tj * 64;

  // ---- stage 192 rows: fp32 -> hi plane (all) + lo plane (own rows) ----
  #pragma unroll
  for (int it = 0; it < 12; it++) {
    int p = tid + it * 512;                      // 6144 f32x4
    int r = p >> 5, cq = p & 31;
    int t = t0 - 128 + r;
    f32x4 v = (f32x4){0.f, 0.f, 0.f, 0.f};
    if (t >= 0) v = *(const f32x4*)(hf_in + ((size_t)b * T + t) * 128 + cq * 4);
    s16x4 phi, plo;
    #pragma unroll
    for (int q = 0; q < 4; q++) {
      u16 hb = f2bf(v[q]);
      phi[q] = (short)hb;
      plo[q] = (short)f2bf(v[q] - bf2f(hb));
    }
    int key = (cq * 8) ^ ((r & 7) << 4);
    *(s16x4*)((char*)hHI + r * 256 + key) = phi;
    if (r >= 128) *(s16x4*)((char*)hLO + (r - 128) * 256 + key) = plo;
  }
  __syncthreads();

  f32x4 sk[2][4];   // skip accumulator (waves 0-3 own it), 32 AGPR
  #pragma unroll
  for (int m = 0; m < 2; m++)
    #pragma unroll
    for (int n = 0; n < 4; n++) sk[m][n] = (f32x4){0.f, 0.f, 0.f, 0.f};

  f32x4 acc[2][4];  // conv / out-GEMM accumulator, 32 AGPR, reused per phase

  #pragma unroll 1
  for (int j = 0; j < 6; j++) {
    const int d = 1 << j;
    const u16* wc = wcv_g + (size_t)j * 3 * 256 * 128;
    const float* cb = cb_g + j * 256;
    const u16* wsl = wso_g + (size_t)j * 256 * 128;
    const float* ob = ob_g + j * 128;
    const int cmin = (j == 5) ? 2 : (j == 4) ? 1 : 0;

    #pragma unroll 1
    for (int ci = 0; ci < 3; ci++) {
      const int c = 2 - ci;            // right-to-left chunks
      if (c < cmin) continue;

      // ---- conv GEMM (a+g): all 8 waves, N = 64 cols ----
      #pragma unroll
      for (int m = 0; m < 2; m++)
        #pragma unroll
        for (int n = 0; n < 4; n++) acc[m][n] = (f32x4){0.f, 0.f, 0.f, 0.f};
      const int oa = wv * 16, og = 128 + wv * 16;
      #pragma unroll
      for (int k = 0; k < 3; k++) {
        const int rb = 64 * c - (2 - k) * d + lo;
        #pragma unroll
        for (int s = 0; s < 4; s++) {
          s16x8 af0 = *(const s16x8*)(wc + (size_t)(k * 256 + oa + lo) * 128 + s * 32 + hi * 8);
          s16x8 af1 = *(const s16x8*)(wc + (size_t)(k * 256 + og + lo) * 128 + s * 32 + hi * 8);
          const int cbyte = s * 64 + hi * 16;
          s16x8 bfr[4];
          #pragma unroll
          for (int n = 0; n < 4; n++) {
            int rr = rb + n * 16;
            if (rr < 0) rr = 0;        // clamped; below-frontier outputs are discarded
            bfr[n] = *(const s16x8*)((const char*)hHI + rr * 256 + (cbyte ^ ((rr & 7) << 4)));
          }
          #pragma unroll
          for (int n = 0; n < 4; n++) {
            acc[0][n] = __builtin_amdgcn_mfma_f32_16x16x32_bf16(af0, bfr[n], acc[0][n], 0, 0, 0);
            acc[1][n] = __builtin_amdgcn_mfma_f32_16x16x32_bf16(af1, bfr[n], acc[1][n], 0, 0, 0);
          }
        }
      }
      // ---- gate -> zh (acc dead after this) ----
      {
        f32x4 ba = *(const f32x4*)(cb + oa + hi * 4);
        f32x4 bg = *(const f32x4*)(cb + og + hi * 4);
        #pragma unroll
        for (int n = 0; n < 4; n++) {
          int u = n * 16 + lo;
          s16x4 pk;
          #pragma unroll
          for (int q = 0; q < 4; q++)
            pk[q] = (short)f2bf(gate_fn(acc[0][n][q] + ba[q], acc[1][n][q] + bg[q]));
          *(s16x4*)((char*)zh + u * 256 + (((oa + hi * 4) * 2) ^ ((u & 7) << 4))) = pk;
        }
      }
      __syncthreads();   // zh ready; all conv h-reads done before in-place writes

      if (c == 2) {
        // ---- own chunk: waves 0-3 skip-GEMM into sk; waves 4-7 out-GEMM (acc) ----
        if (wv < 4) {
          const int ro = wv * 32;
          #pragma unroll
          for (int s = 0; s < 4; s++) {
            s16x8 af0 = *(const s16x8*)(wsl + (size_t)(ro + lo) * 128 + s * 32 + hi * 8);
            s16x8 af1 = *(const s16x8*)(wsl + (size_t)(ro + 16 + lo) * 128 + s * 32 + hi * 8);
            const int cbyte = s * 64 + hi * 16;
            s16x8 bfr[4];
            #pragma unroll
            for (int n = 0; n < 4; n++) {
              int u = n * 16 + lo;
              bfr[n] = *(const s16x8*)((const char*)zh + u * 256 + (cbyte ^ ((u & 7) << 4)));
            }
            #pragma unroll
            for (int n = 0; n < 4; n++) {
              sk[0][n] = __builtin_amdgcn_mfma_f32_16x16x32_bf16(af0, bfr[n], sk[0][n], 0, 0, 0);
              sk[1][n] = __builtin_amdgcn_mfma_f32_16x16x32_bf16(af1, bfr[n], sk[1][n], 0, 0, 0);
            }
          }
        } else {
          const int ro = (wv - 4) * 32;
          #pragma unroll
          for (int m = 0; m < 2; m++)
            #pragma unroll
            for (int n = 0; n < 4; n++) acc[m][n] = (f32x4){0.f, 0.f, 0.f, 0.f};
          #pragma unroll
          for (int s = 0; s < 4; s++) {
            s16x8 af0 = *(const s16x8*)(wsl + (size_t)(128 + ro + lo) * 128 + s * 32 + hi * 8);
            s16x8 af1 = *(const s16x8*)(wsl + (size_t)(128 + ro + 16 + lo) * 128 + s * 32 + hi * 8);
            const int cbyte = s * 64 + hi * 16;
            s16x8 bfr[4];
            #pragma unroll
            for (int n = 0; n < 4; n++) {
              int u = n * 16 + lo;
              bfr[n] = *(const s16x8*)((const char*)zh + u * 256 + (cbyte ^ ((u & 7) << 4)));
            }
            #pragma unroll
            for (int n = 0; n < 4; n++) {
              acc[0][n] = __builtin_amdgcn_mfma_f32_16x16x32_bf16(af0, bfr[n], acc[0][n], 0, 0, 0);
              acc[1][n] = __builtin_amdgcn_mfma_f32_16x16x32_bf16(af1, bfr[n], acc[1][n], 0, 0, 0);
            }
          }
          #pragma unroll
          for (int m = 0; m < 2; m++) {
            int c0 = ro + m * 16 + hi * 4;
            f32x4 ob4 = *(const f32x4*)(ob + c0);
            #pragma unroll
            for (int n = 0; n < 4; n++) {
              int u = n * 16 + lo;
              int r = 128 + u;
              int key = (c0 * 2) ^ ((r & 7) << 4);
              s16x4 vhi = *(const s16x4*)((const char*)hHI + r * 256 + key);
              s16x4 vlo = *(const s16x4*)((const char*)hLO + u * 256 + key);
              f32x4 hold;
              #pragma unroll
              for (int q = 0; q < 4; q++)
                hold[q] = bf2f((u16)vhi[q]) + bf2f((u16)vlo[q]);
              f32x4 hnew = (acc[m][n] + ob4 + hold) * SH;
              if (j == 5) {
                *(f32x4*)(hf_out + ((size_t)b * T + t0 + u) * 128 + c0) = hnew;
              } else {
                s16x4 nhi, nlo;
                #pragma unroll
                for (int q = 0; q < 4; q++) {
                  u16 hb = f2bf(hnew[q]);
                  nhi[q] = (short)hb;
                  nlo[q] = (short)f2bf(hnew[q] - bf2f(hb));
                }
                *(s16x4*)((char*)hHI + r * 256 + key) = nhi;
                *(s16x4*)((char*)hLO + u * 256 + key) = nlo;
              }
            }
          }
        }
      } else {
        // ---- redundant chunk: ALL 8 waves out-GEMM (16 rows each), reuse acc[0] ----
        const int ro = wv * 16;
        #pragma unroll
        for (int n = 0; n < 4; n++) acc[0][n] = (f32x4){0.f, 0.f, 0.f, 0.f};
        #pragma unroll
        for (int s = 0; s < 4; s++) {
          s16x8 af0 = *(const s16x8*)(wsl + (size_t)(128 + ro + lo) * 128 + s * 32 + hi * 8);
          const int cbyte = s * 64 + hi * 16;
          s16x8 bfr[4];
          #pragma unroll
          for (int n = 0; n < 4; n++) {
            int u = n * 16 + lo;
            bfr[n] = *(const s16x8*)((const char*)zh + u * 256 + (cbyte ^ ((u & 7) << 4)));
          }
          #pragma unroll
          for (int n = 0; n < 4; n++)
            acc[0][n] = __builtin_amdgcn_mfma_f32_16x16x32_bf16(af0, bfr[n], acc[0][n], 0, 0, 0);
        }
        {
          int c0 = ro + hi * 4;
          f32x4 ob4 = *(const f32x4*)(ob + c0);
          #pragma unroll
          for (int n = 0; n < 4; n++) {
            int u = n * 16 + lo;
            int r = 64 * c + u;
            int key = (c0 * 2) ^ ((r & 7) << 4);
            s16x4 vhi = *(const s16x4*)((const char*)hHI + r * 256 + key);
            f32x4 hold;
            #pragma unroll
            for (int q = 0; q < 4; q++) hold[q] = bf2f((u16)vhi[q]);
            f32x4 hnew = (acc[0][n] + ob4 + hold) * SH;
            s16x4 nhi;
            #pragma unroll
            for (int q = 0; q < 4; q++) nhi[q] = (short)f2bf(hnew[q]);
            *(s16x4*)((char*)hHI + r * 256 + key) = nhi;
          }
        }
      }
      __syncthreads();   // h updates visible before next chunk/layer conv
    }
  }

  // ---- skip writeback: one RMW per group ----
  if (wv < 4) {
    #pragma unroll
    for (int m = 0; m < 2; m++) {
      int c0 = wv * 32 + m * 16 + hi * 4;
      #pragma unroll
      for (int n = 0; n < 4; n++) {
        int t = t0 + n * 16 + lo;
        size_t off = ((size_t)b * T + t) * 128 + c0;
        f32x4 r = sk[m][n];
        if (!first) r += *(const f32x4*)(skip + off);
        *(f32x4*)(skip + off) = r;
      }
    }
  }
}

// ==================== FALLBACK: R7 pair-kernel path (known-good, 697us) ====================
__global__ __launch_bounds__(512, 4)
void pair_kernel(const float* __restrict__ hf_in, float* __restrict__ hf_out,
                 float* __restrict__ skip,
                 const u16* __restrict__ wc1, const float* __restrict__ cb1,
                 const u16* __restrict__ ws1, const float* __restrict__ ob1,
                 const u16* __restrict__ wc2, const float* __restrict__ cb2,
                 const u16* __restrict__ ws2, const float* __restrict__ ob2,
                 int d1, int d2, int first) {
  extern __shared__ u16 lds[];
  u16* h_s = lds;
  u16* zh  = lds + 160 * 128;
  const int tid = threadIdx.x, wv = tid >> 6, lane = tid & 63, lo = lane & 15, hi = lane >> 4;
  const int tj = blockIdx.x, b = blockIdx.y, t0 = tj * 64;
  const int R0 = 128 + 2 * d1;

  for (int p = tid; p < R0 * 32; p += 512) {
    int j0 = p >> 5, cq = p & 31;
    int t = t0 - 64 - 2 * d1 + j0;
    f32x4 v = (f32x4){0.f, 0.f, 0.f, 0.f};
    if (t >= 0) v = *(const f32x4*)(hf_in + ((size_t)b * T + t) * 128 + cq * 4);
    s16x4 pk;
    #pragma unroll
    for (int j = 0; j < 4; j++) pk[j] = (short)f2bf(v[j]);
    *(s16x4*)((char*)h_s + j0 * 256 + ((cq * 8) ^ (((j0 + 64 - 2 * d1) & 7) << 4))) = pk;
  }
  __syncthreads();

  f32x4 A[2][8];
  const int oa = wv * 16, og = 128 + wv * 16;

  #pragma unroll
  for (int m = 0; m < 2; m++)
    #pragma unroll
    for (int n = 0; n < 8; n++) A[m][n] = (f32x4){0.f, 0.f, 0.f, 0.f};
  #pragma unroll
  for (int k = 0; k < 3; k++) {
    const int st = ((lo + (k + 6) * d1) & 7) << 4;
    const int jb = k * d1;
    #pragma unroll
    for (int s = 0; s < 4; s++) {
      s16x8 af0 = *(const s16x8*)(wc1 + ((size_t)(k * 256 + oa + lo)) * 128 + s * 32 + hi * 8);
      s16x8 af1 = *(const s16x8*)(wc1 + ((size_t)(k * 256 + og + lo)) * 128 + s * 32 + hi * 8);
      const int cb_ = s * 64 + hi * 16;
      #pragma unroll
      for (int h2 = 0; h2 < 2; h2++) {
        s16x8 bf[4];
        #pragma unroll
        for (int nn = 0; nn < 4; nn++) {
          int j0 = (h2 * 4 + nn) * 16 + lo + jb;
          bf[nn] = *(const s16x8*)((const char*)h_s + j0 * 256 + (cb_ ^ st));
        }
        #pragma unroll
        for (int nn = 0; nn < 4; nn++) {
          A[0][h2 * 4 + nn] = __builtin_amdgcn_mfma_f32_16x16x32_bf16(af0, bf[nn], A[0][h2 * 4 + nn], 0, 0, 0);
          A[1][h2 * 4 + nn] = __builtin_amdgcn_mfma_f32_16x16x32_bf16(af1, bf[nn], A[1][h2 * 4 + nn], 0, 0, 0);
        }
      }
    }
  }
  {
    f32x4 ba = *(const f32x4*)(cb1 + oa + hi * 4);
    f32x4 bg = *(const f32x4*)(cb1 + og + hi * 4);
    #pragma unroll
    for (int n = 0; n < 8; n++) {
      int u = n * 16 + lo;
      s16x4 pk;
      #pragma unroll
      for (int j = 0; j < 4; j++)
        pk[j] = (short)f2bf(gate_fn(A[0][n][j] + ba[j], A[1][n][j] + bg[j]));
      *(s16x4*)((char*)zh + u * 256 + (((oa + hi * 4) * 2) ^ ((lo & 7) << 4))) = pk;
    }
  }
  __syncthreads();

  const int ro = wv * 32;
  if (wv < 4) {
    #pragma unroll
    for (int m = 0; m < 2; m++)
      #pragma unroll
      for (int nn = 0; nn < 4; nn++) A[m][nn + 4] = (f32x4){0.f, 0.f, 0.f, 0.f};
    #pragma unroll
    for (int s = 0; s < 4; s++) {
      s16x8 af0 = *(const s16x8*)(ws1 + (size_t)(ro + lo) * 128 + s * 32 + hi * 8);
      s16x8 af1 = *(const s16x8*)(ws1 + (size_t)(ro + 16 + lo) * 128 + s * 32 + hi * 8);
      const int cb_ = s * 64 + hi * 16;
      s16x8 bf[4];
      #pragma unroll
      for (int nn = 0; nn < 4; nn++) {
        int u = (nn + 4) * 16 + lo;
        bf[nn] = *(const s16x8*)((const char*)zh + u * 256 + (cb_ ^ ((lo & 7) << 4)));
      }
      #pragma unroll
      for (int nn = 0; nn < 4; nn++) {
        A[0][nn + 4] = __builtin_amdgcn_mfma_f32_16x16x32_bf16(af0, bf[nn], A[0][nn + 4], 0, 0, 0);
        A[1][nn + 4] = __builtin_amdgcn_mfma_f32_16x16x32_bf16(af1, bf[nn], A[1][nn + 4], 0, 0, 0);
      }
    }
  } else {
    #pragma unroll
    for (int m = 0; m < 2; m++)
      #pragma unroll
      for (int n = 0; n < 8; n++) A[m][n] = (f32x4){0.f, 0.f, 0.f, 0.f};
    #pragma unroll
    for (int s = 0; s < 4; s++) {
      s16x8 af0 = *(const s16x8*)(ws1 + (size_t)(ro + lo) * 128 + s * 32 + hi * 8);
      s16x8 af1 = *(const s16x8*)(ws1 + (size_t)(ro + 16 + lo) * 128 + s * 32 + hi * 8);
      const int cb_ = s * 64 + hi * 16;
      #pragma unroll
      for (int h2 = 0; h2 < 2; h2++) {
        s16x8 bf[4];
        #pragma unroll
        for (int nn = 0; nn < 4; nn++) {
          int u = (h2 * 4 + nn) * 16 + lo;
          bf[nn] = *(const s16x8*)((const char*)zh + u * 256 + (cb_ ^ ((lo & 7) << 4)));
        }
        #pragma unroll
        for (int nn = 0; nn < 4; nn++) {
          A[0][h2 * 4 + nn] = __builtin_amdgcn_mfma_f32_16x16x32_bf16(af0, bf[nn], A[0][h2 * 4 + nn], 0, 0, 0);
          A[1][h2 * 4 + nn] = __builtin_amdgcn_mfma_f32_16x16x32_bf16(af1, bf[nn], A[1][h2 * 4 + nn], 0, 0, 0);
        }
      }
    }
    #pragma unroll
    for (int m = 0; m < 2; m++) {
      int c0 = (wv - 4) * 32 + m * 16 + hi * 4;
      f32x4 ob4 = *(const f32x4*)(ob1 + c0);
      #pragma unroll
      for (int n = 0; n < 8; n++) {
        int u = n * 16 + lo;
        int t_out = t0 - 64 + u;
        f32x4 h0 = (f32x4){0.f, 0.f, 0.f, 0.f};
        if (t_out >= 0) h0 = *(const f32x4*)(hf_in + ((size_t)b * T + t_out) * 128 + c0);
        f32x4 h1 = (A[m][n] + ob4 + h0) * SH;
        if (t_out < 0) h1 = (f32x4){0.f, 0.f, 0.f, 0.f};
        A[m][n] = h1;
        s16x4 pk;
        #pragma unroll
        for (int j = 0; j < 4; j++) pk[j] = (short)f2bf(h1[j]);
        *(s16x4*)((char*)h_s + u * 256 + ((c0 * 2) ^ ((lo & 7) << 4))) = pk;
      }
    }
  }
  __syncthreads();

  #pragma unroll
  for (int m = 0; m < 2; m++)
    #pragma unroll
    for (int n = 0; n < 4; n++) A[m][n] = (f32x4){0.f, 0.f, 0.f, 0.f};
  #pragma unroll
  for (int k = 0; k < 3; k++) {
    const int st = ((lo + (k + 6) * d2) & 7) << 4;
    const int jb2 = 64 - 2 * d2 + k * d2;
    #pragma unroll
    for (int s = 0; s < 4; s++) {
      s16x8 af0 = *(const s16x8*)(wc2 + ((size_t)(k * 256 + oa + lo)) * 128 + s * 32 + hi * 8);
      s16x8 af1 = *(const s16x8*)(wc2 + ((size_t)(k * 256 + og + lo)) * 128 + s * 32 + hi * 8);
      const int cb_ = s * 64 + hi * 16;
      s16x8 bf[4];
      #pragma unroll
      for (int nn = 0; nn < 4; nn++) {
        int j1 = nn * 16 + lo + jb2;
        bf[nn] = *(const s16x8*)((const char*)h_s + j1 * 256 + (cb_ ^ st));
      }
      #pragma unroll
      for (int nn = 0; nn < 4; nn++) {
        A[0][nn] = __builtin_amdgcn_mfma_f32_16x16x32_bf16(af0, bf[nn], A[0][nn], 0, 0, 0);
        A[1][nn] = __builtin_amdgcn_mfma_f32_16x16x32_bf16(af1, bf[nn], A[1][nn], 0, 0, 0);
      }
    }
  }
  {
    f32x4 ba = *(const f32x4*)(cb2 + oa + hi * 4);
    f32x4 bg = *(const f32x4*)(cb2 + og + hi * 4);
    #pragma unroll
    for (int n = 0; n < 4; n++) {
      int u = n * 16 + lo;
      s16x4 pk;
      #pragma unroll
      for (int j = 0; j < 4; j++)
        pk[j] = (short)f2bf(gate_fn(A[0][n][j] + ba[j], A[1][n][j] + bg[j]));
      *(s16x4*)((char*)zh + u * 256 + (((oa + hi * 4) * 2) ^ ((lo & 7) << 4))) = pk;
    }
  }
  __syncthreads();

  if (wv < 4) {
    #pragma unroll
    for (int s = 0; s < 4; s++) {
      s16x8 af0 = *(const s16x8*)(ws2 + (size_t)(ro + lo) * 128 + s * 32 + hi * 8);
      s16x8 af1 = *(const s16x8*)(ws2 + (size_t)(ro + 16 + lo) * 128 + s * 32 + hi * 8);
      const int cb_ = s * 64 + hi * 16;
      s16x8 bf[4];
      #pragma unroll
      for (int nn = 0; nn < 4; nn++) {
        int u = nn * 16 + lo;
        bf[nn] = *(const s16x8*)((const char*)zh + u * 256 + (cb_ ^ ((lo & 7) << 4)));
      }
      #pragma unroll
      for (int nn = 0; nn < 4; nn++) {
        A[0][nn + 4] = __builtin_amdgcn_mfma_f32_16x16x32_bf16(af0, bf[nn], A[0][nn + 4], 0, 0, 0);
        A[1][nn + 4] = __builtin_amdgcn_mfma_f32_16x16x32_bf16(af1, bf[nn], A[1][nn + 4], 0, 0, 0);
      }
    }
    #pragma unroll
    for (int m = 0; m < 2; m++) {
      int c0 = ro + m * 16 + hi * 4;
      #pragma unroll
      for (int n = 0; n < 4; n++) {
        int t = t0 + n * 16 + lo;
        size_t off = ((size_t)b * T + t) * 128 + c0;
        f32x4 r = A[m][n + 4];
        if (!first) r += *(const f32x4*)(skip + off);
        *(f32x4*)(skip + off) = r;
      }
    }
  } else {
    #pragma unroll
    for (int m = 0; m < 2; m++)
      #pragma unroll
      for (int n = 0; n < 4; n++) A[m][n] = (f32x4){0.f, 0.f, 0.f, 0.f};
    #pragma unroll
    for (int s = 0; s < 4; s++) {
      s16x8 af0 = *(const s16x8*)(ws2 + (size_t)(ro + lo) * 128 + s * 32 + hi * 8);
      s16x8 af1 = *(const s16x8*)(ws2 + (size_t)(ro + 16 + lo) * 128 + s * 32 + hi * 8);
      const int cb_ = s * 64 + hi * 16;
      s16x8 bf[4];
      #pragma unroll
      for (int nn = 0; nn < 4; nn++) {
        int u = nn * 16 + lo;
        bf[nn] = *(const s16x8*)((const char*)zh + u * 256 + (cb_ ^ ((lo & 7) << 4)));
      }
      #pragma unroll
      for (int nn = 0; nn < 4; nn++) {
        A[0][nn] = __builtin_amdgcn_mfma_f32_16x16x32_bf16(af0, bf[nn], A[0][nn], 0, 0, 0);
        A[1][nn] = __builtin_amdgcn_mfma_f32_16x16x32_bf16(af1, bf[nn], A[1][nn], 0, 0, 0);
      }
    }
    #pragma unroll
    for (int m = 0; m < 2; m++) {
      int c0 = (wv - 4) * 32 + m * 16 + hi * 4;
      f32x4 ob4 = *(const f32x4*)(ob2 + c0);
      #pragma unroll
      for (int n = 0; n < 4; n++) {
        int t = t0 + n * 16 + lo;
        f32x4 h2v = (A[m][n] + ob4 + A[m][n + 4]) * SH;
        *(f32x4*)(hf_out + ((size_t)b * T + t) * 128 + c0) = h2v;
      }
    }
  }
}

// ---------------- fused head ----------------
__global__ __launch_bounds__(256, 2)
void head_kernel(const float* __restrict__ skip, const float* __restrict__ sumsb,
                 const u16* __restrict__ w1, const float* __restrict__ b1v,
                 const u16* __restrict__ w2, const float* __restrict__ b2v,
                 float* __restrict__ out) {
  __shared__ u16 sT[64 * 128];
  __shared__ u16 s1T[64 * 128];
  const int tid = threadIdx.x, wv = tid >> 6, lane = tid & 63, lo = lane & 15, hi = lane >> 4;
  const int t0 = blockIdx.x * 64, b = blockIdx.y;

  #pragma unroll
  for (int it = 0; it < 8; it++) {
    int p = tid + it * 256;
    int t = p >> 5, cq = p & 31;
    f32x4 v = *(const f32x4*)(skip + ((size_t)b * T + t0 + t) * 128 + cq * 4);
    f32x4 sb4 = *(const f32x4*)(sumsb + cq * 4);
    s16x4 pk;
    #pragma unroll
    for (int j = 0; j < 4; j++) pk[j] = (short)f2bf(fmaxf((v[j] + sb4[j]) * SKIP_SCALE, 0.f));
    *(s16x4*)((char*)sT + t * 256 + ((cq * 8) ^ ((t & 7) << 4))) = pk;
  }
  __syncthreads();
  {
    f32x4 acc[2][4];
    #pragma unroll
    for (int m = 0; m < 2; m++)
      #pragma unroll
      for (int n = 0; n < 4; n++) acc[m][n] = (f32x4){0.f, 0.f, 0.f, 0.f};
    #pragma unroll
    for (int s = 0; s < 4; s++) {
      s16x8 af0 = *(const s16x8*)(w1 + (size_t)(wv * 32 + lo) * 128 + s * 32 + hi * 8);
      s16x8 af1 = *(const s16x8*)(w1 + (size_t)(wv * 32 + 16 + lo) * 128 + s * 32 + hi * 8);
      #pragma unroll
      for (int n = 0; n < 4; n++) {
        int t = n * 16 + lo;
        s16x8 bf = *(const s16x8*)((const char*)sT + t * 256 + ((s * 64 + hi * 16) ^ ((t & 7) << 4)));
        acc[0][n] = __builtin_amdgcn_mfma_f32_16x16x32_bf16(af0, bf, acc[0][n], 0, 0, 0);
        acc[1][n] = __builtin_amdgcn_mfma_f32_16x16x32_bf16(af1, bf, acc[1][n], 0, 0, 0);
      }
    }
    #pragma unroll
    for (int m = 0; m < 2; m++) {
      int c0 = wv * 32 + m * 16 + hi * 4;
      f32x4 bv = *(const f32x4*)(b1v + c0);
      #pragma unroll
      for (int n = 0; n < 4; n++) {
        int t = n * 16 + lo;
        s16x4 pk;
        #pragma unroll
        for (int j = 0; j < 4; j++) pk[j] = (short)f2bf(fmaxf(acc[m][n][j] + bv[j], 0.f));
        *(s16x4*)((char*)s1T + t * 256 + ((c0 * 2) ^ ((t & 7) << 4))) = pk;
      }
    }
  }
  __syncthreads();
  {
    f32x4 acc[4][4];
    #pragma unroll
    for (int m = 0; m < 4; m++)
      #pragma unroll
      for (int n = 0; n < 4; n++) acc[m][n] = (f32x4){0.f, 0.f, 0.f, 0.f};
    #pragma unroll
    for (int s = 0; s < 4; s++) {
      s16x8 af[4];
      #pragma unroll
      for (int m = 0; m < 4; m++)
        af[m] = *(const s16x8*)(w2 + (size_t)(wv * 64 + m * 16 + lo) * 128 + s * 32 + hi * 8);
      #pragma unroll
      for (int n = 0; n < 4; n++) {
        int t = n * 16 + lo;
        s16x8 bf = *(const s16x8*)((const char*)s1T + t * 256 + ((s * 64 + hi * 16) ^ ((t & 7) << 4)));
        #pragma unroll
        for (int m = 0; m < 4; m++)
          acc[m][n] = __builtin_amdgcn_mfma_f32_16x16x32_bf16(af[m], bf, acc[m][n], 0, 0, 0);
      }
    }
    #pragma unroll
    for (int m = 0; m < 4; m++) {
      int c0 = wv * 64 + m * 16 + hi * 4;
      f32x4 bv = *(const f32x4*)(b2v + c0);
      #pragma unroll
      for (int n = 0; n < 4; n++) {
        int t = t0 + n * 16 + lo;
        f32x4 r = acc[m][n] + bv;
        #pragma unroll
        for (int j = 0; j < 4; j++) out[((size_t)b * CIN + c0 + j) * T + t] = r[j];
      }
    }
  }
}

// ---------------------------------------------------------------------------
extern "C" void kernel_launch(void* const* d_in, const int* in_sizes, int n_in,
                              void* d_out, int out_size, void* d_ws, size_t ws_size,
                              hipStream_t stream) {
  const float* x       = (const float*)d_in[0];
  const float* first_w = (const float*)d_in[1];
  const float* first_b = (const float*)d_in[2];
  const float* conv_w  = (const float*)d_in[3];
  const float* conv_b  = (const float*)d_in[4];
  const float* out_w   = (const float*)d_in[5];
  const float* out_b   = (const float*)d_in[6];
  const float* skip_w  = (const float*)d_in[7];
  const float* skip_b  = (const float*)d_in[8];
  const float* last1_w = (const float*)d_in[9];
  const float* last1_b = (const float*)d_in[10];
  const float* last2_w = (const float*)d_in[11];
  const float* last2_b = (const float*)d_in[12];
  float* outp = (float*)d_out;

  u16* wcv = (u16*)d_ws;
  u16* wso = wcv + (size_t)NL * 3 * 256 * 128;
  u16* wfB = wso + (size_t)NL * 256 * 128;
  u16* w1B = wfB + 128 * 256;
  u16* w2B = w1B + 128 * 128;
  float* sumsb = (float*)(w2B + 256 * 128);
  float* skipF = sumsb + 128;                    // 16MB fp32 skip accumulator
  float* hfA = (float*)d_out;                    // residual double-buffer in d_out
  float* hfB = hfA + (size_t)B * T * 128;

  cvt_all<<<12608, 256, 0, stream>>>(conv_w, skip_w, out_w, first_w, last1_w, last2_w,
                                     wcv, wso, wfB, w1B, w2B);
  sumsb_kernel<<<1, 128, 0, stream>>>(skip_b, sumsb);

  dim3 g64(T / 64, B);
  first_kernel<<<g64, 256, 0, stream>>>(x, wfB, first_b, hfA);

  (void)hipFuncSetAttribute((const void*)group6_kernel,
                            hipFuncAttributeMaxDynamicSharedMemorySize, 81920);
  (void)hipGetLastError();

  group6_kernel<<<g64, 512, 81920, stream>>>(hfA, hfB, skipF, wcv, conv_b, wso, out_b, 1);
  hipError_t ce = hipGetLastError();

  if (ce == hipSuccess) {
    for (int g = 1; g < 4; g++) {
      const float* hin = (g & 1) ? hfB : hfA;
      float* hout = (g & 1) ? hfA : hfB;
      group6_kernel<<<g64, 512, 81920, stream>>>(
          hin, hout, skipF,
          wcv + (size_t)g * 6 * 3 * 256 * 128, conv_b + (size_t)g * 6 * 256,
          wso + (size_t)g * 6 * 256 * 128, out_b + (size_t)g * 6 * 128, 0);
    }
  } else {
    // fallback: known-good pair chain (hfA already populated by first_kernel)
    for (int p = 0; p < NL / 2; p++) {
      int l1 = 2 * p, l2 = 2 * p + 1;
      int d1 = 1 << (l1 % 6), d2 = 1 << (l2 % 6);
      const float* hin = (p & 1) ? hfB : hfA;
      float* hout = (p & 1) ? hfA : hfB;
      pair_kernel<<<g64, 512, 73728, stream>>>(
          hin, hout, skipF,
          wcv + (size_t)l1 * 3 * 256 * 128, conv_b + (size_t)l1 * 256,
          wso + (size_t)l1 * 256 * 128, out_b + (size_t)l1 * 128,
          wcv + (size_t)l2 * 3 * 256 * 128, conv_b + (size_t)l2 * 256,
          wso + (size_t)l2 * 256 * 128, out_b + (size_t)l2 * 128,
          d1, d2, p == 0 ? 1 : 0);
    }
  }
  head_kernel<<<g64, 256, 0, stream>>>(skipF, sumsb, w1B, last1_b, w2B, last2_b, outp);
}

// Round 13
// 700.517 us; speedup vs baseline: 1.7344x; 1.7337x over previous
//
#include <hip/hip_runtime.h>

#define B 4
#define CIN 256
#define T 8192
#define NL 24
#define SH 0.70710678118654752f
#define SKIP_SCALE 0.20412414523193150f  // (1/24)^0.5

typedef unsigned short u16;
typedef __attribute__((ext_vector_type(4))) float f32x4;
typedef __attribute__((ext_vector_type(8))) short s16x8;
typedef __attribute__((ext_vector_type(4))) short s16x4;

__device__ inline u16 f2bf(float f) {            // RNE float->bf16
  unsigned u = __float_as_uint(f);
  return (u16)((u + 0x7fffu + ((u >> 16) & 1u)) >> 16);
}
__device__ inline float gate_fn(float a, float g) {
  float e2 = __expf(-2.f * fabsf(a));
  float th = (1.f - e2) * __builtin_amdgcn_rcpf(1.f + e2);
  float sg = __builtin_amdgcn_rcpf(1.f + __expf(-g));
  return copysignf(th, a) * sg;
}
__device__ inline void gload_lds16(const void* g, void* l) {
  __builtin_amdgcn_global_load_lds(
      (const __attribute__((address_space(1))) unsigned*)g,
      (__attribute__((address_space(3))) unsigned*)l, 16, 0, 0);
}

// ---------------- weight prep (merged) ----------------
__global__ void cvt_all(const float* __restrict__ conv_w, const float* __restrict__ skip_w,
                        const float* __restrict__ out_w, const float* __restrict__ first_w,
                        const float* __restrict__ last1_w, const float* __restrict__ last2_w,
                        u16* __restrict__ wcv, u16* __restrict__ wso, u16* __restrict__ wf,
                        u16* __restrict__ w1, u16* __restrict__ w2) {
  int i = blockIdx.x * 256 + threadIdx.x;
  if (i < 2359296) {  // conv: dst [l][k][o][c] <- src [l][o][c][k]
    int c = i & 127, o = (i >> 7) & 255, kk = (i >> 15) % 3, l = (i >> 15) / 3;
    wcv[i] = f2bf(conv_w[(((size_t)l * 256 + o) * 128 + c) * 3 + kk]);
    return;
  }
  i -= 2359296;
  if (i < 786432) {
    int c = i & 127, r = (i >> 7) & 255, l = i >> 15;
    float v = (r < 128) ? skip_w[((size_t)l * 128 + r) * 128 + c]
                        : out_w[((size_t)l * 128 + (r - 128)) * 128 + c];
    wso[i] = f2bf(v);
    return;
  }
  i -= 786432;
  if (i < 32768) { wf[i] = f2bf(first_w[i]); return; }
  i -= 32768;
  if (i < 16384) { w1[i] = f2bf(last1_w[i]); return; }
  i -= 16384;
  if (i < 32768) { w2[i] = f2bf(last2_w[i]); return; }
}
__global__ void sumsb_kernel(const float* __restrict__ sb, float* __restrict__ dst) {
  int c = threadIdx.x;  // 128
  float s = 0.f;
  for (int l = 0; l < NL; l++) s += sb[l * 128 + c];
  dst[c] = s;
}

// ---------------- first conv: hf = first_w @ x + first_b; also write bf16 shadow ----------------
// Shadow layout: u16 at [(b*T + t)*128 + (c ^ ((t&7)<<3))]  (pre-swizzled by the
// same key the LDS tiles use, so staging is a LINEAR copy / global_load_lds).
__global__ __launch_bounds__(256, 2)
void first_kernel(const float* __restrict__ x, const u16* __restrict__ wf,
                  const float* __restrict__ fb, float* __restrict__ hf,
                  u16* __restrict__ sh) {
  __shared__ u16 xT[64 * 256];
  const int tid = threadIdx.x, wv = tid >> 6, lane = tid & 63, lo = lane & 15, hi = lane >> 4;
  const int t0 = blockIdx.x * 64, b = blockIdx.y;
  #pragma unroll
  for (int it = 0; it < 16; it++) {
    int idx = tid + it * 256;
    int c = idx >> 4, t4 = (idx & 15) << 2;
    f32x4 v = *(const f32x4*)(x + ((size_t)b * CIN + c) * T + t0 + t4);
    #pragma unroll
    for (int i = 0; i < 4; i++) {
      int t = t4 + i;
      *(u16*)((char*)xT + t * 512 + ((c * 2) ^ ((t & 7) << 4))) = f2bf(v[i]);
    }
  }
  __syncthreads();
  f32x4 acc[2][4];
  #pragma unroll
  for (int m = 0; m < 2; m++)
    #pragma unroll
    for (int n = 0; n < 4; n++) acc[m][n] = (f32x4){0.f, 0.f, 0.f, 0.f};
  #pragma unroll
  for (int s = 0; s < 8; s++) {
    s16x8 af[2], bf[4];
    #pragma unroll
    for (int m = 0; m < 2; m++)
      af[m] = *(const s16x8*)(wf + (size_t)(wv * 32 + m * 16 + lo) * CIN + s * 32 + hi * 8);
    #pragma unroll
    for (int n = 0; n < 4; n++) {
      int t = n * 16 + lo;
      bf[n] = *(const s16x8*)((const char*)xT + t * 512 + ((s * 64 + hi * 16) ^ ((t & 7) << 4)));
    }
    #pragma unroll
    for (int m = 0; m < 2; m++)
      #pragma unroll
      for (int n = 0; n < 4; n++)
        acc[m][n] = __builtin_amdgcn_mfma_f32_16x16x32_bf16(af[m], bf[n], acc[m][n], 0, 0, 0);
  }
  #pragma unroll
  for (int m = 0; m < 2; m++) {
    int c0 = wv * 32 + m * 16 + hi * 4;
    f32x4 bv = *(const f32x4*)(fb + c0);
    #pragma unroll
    for (int n = 0; n < 4; n++) {
      int t = t0 + n * 16 + lo;
      f32x4 h = acc[m][n] + bv;
      *(f32x4*)(hf + ((size_t)b * T + t) * 128 + c0) = h;
      s16x4 pk;
      #pragma unroll
      for (int j = 0; j < 4; j++) pk[j] = (short)f2bf(h[j]);
      // shadow write: key = (t&7)<<3 = (lo&7)<<3 (t0%8==0, (n*16)%8==0)
      *(s16x4*)(sh + ((size_t)b * T + t) * 128 + (c0 ^ ((lo & 7) << 3))) = pk;
    }
  }
}

// ---------------- pair kernel (R7 structure; staging via shadow) ----------------
__global__ __launch_bounds__(512, 4)
void pair_kernel(const float* __restrict__ hf_in, float* __restrict__ hf_out,
                 const u16* __restrict__ sh_in, u16* __restrict__ sh_out,
                 float* __restrict__ skip,
                 const u16* __restrict__ wc1, const float* __restrict__ cb1,
                 const u16* __restrict__ ws1, const float* __restrict__ ob1,
                 const u16* __restrict__ wc2, const float* __restrict__ cb2,
                 const u16* __restrict__ ws2, const float* __restrict__ ob2,
                 int d1, int d2, int first) {
  extern __shared__ u16 lds[];
  u16* h_s = lds;              // 160 rows x 256B = 40KB
  u16* zh  = lds + 160 * 128;  // 128 rows x 256B = 32KB
  const int tid = threadIdx.x, wv = tid >> 6, lane = tid & 63, lo = lane & 15, hi = lane >> 4;
  const int tj = blockIdx.x, b = blockIdx.y, t0 = tj * 64;
  const int R0 = 128 + 2 * d1;
  const int base_t = t0 - 64 - 2 * d1;   // t of LDS row 0

  // ---- stage: shadow (pre-swizzled bf16) -> LDS, pure linear copy ----
  if (base_t >= 0) {
    // fast path: async global->LDS, 1KB (4 rows) per wave-iteration
    const char* src = (const char*)(sh_in + ((size_t)b * T + base_t) * 128);
    for (int rr = wv * 4; rr < R0; rr += 32)
      gload_lds16(src + rr * 256 + lane * 16, (char*)h_s + rr * 256);
  } else {
    // boundary blocks (tj<=1): linear copy with zero rows for t<0
    for (int p = tid; p < R0 * 16; p += 512) {
      int r = p >> 4, q = p & 15;
      int t = base_t + r;
      s16x8 v = (s16x8){0, 0, 0, 0, 0, 0, 0, 0};
      if (t >= 0) v = *(const s16x8*)(sh_in + ((size_t)b * T + t) * 128 + q * 8);
      *(s16x8*)((char*)h_s + r * 256 + q * 16) = v;
    }
  }
  __syncthreads();

  f32x4 A[2][8];
  const int oa = wv * 16, og = 128 + wv * 16;

  // ---- conv1 GEMM: N=128 cols ----
  #pragma unroll
  for (int m = 0; m < 2; m++)
    #pragma unroll
    for (int n = 0; n < 8; n++) A[m][n] = (f32x4){0.f, 0.f, 0.f, 0.f};
  #pragma unroll
  for (int k = 0; k < 3; k++) {
    const int st = ((lo + (k + 6) * d1) & 7) << 4;
    const int jb = k * d1;
    #pragma unroll
    for (int s = 0; s < 4; s++) {
      s16x8 af0 = *(const s16x8*)(wc1 + ((size_t)(k * 256 + oa + lo)) * 128 + s * 32 + hi * 8);
      s16x8 af1 = *(const s16x8*)(wc1 + ((size_t)(k * 256 + og + lo)) * 128 + s * 32 + hi * 8);
      const int cb_ = s * 64 + hi * 16;
      #pragma unroll
      for (int h2 = 0; h2 < 2; h2++) {
        s16x8 bf[4];
        #pragma unroll
        for (int nn = 0; nn < 4; nn++) {
          int j0 = (h2 * 4 + nn) * 16 + lo + jb;
          bf[nn] = *(const s16x8*)((const char*)h_s + j0 * 256 + (cb_ ^ st));
        }
        #pragma unroll
        for (int nn = 0; nn < 4; nn++) {
          A[0][h2 * 4 + nn] = __builtin_amdgcn_mfma_f32_16x16x32_bf16(af0, bf[nn], A[0][h2 * 4 + nn], 0, 0, 0);
          A[1][h2 * 4 + nn] = __builtin_amdgcn_mfma_f32_16x16x32_bf16(af1, bf[nn], A[1][h2 * 4 + nn], 0, 0, 0);
        }
      }
    }
  }
  // ---- gate1 -> zh (128 cols) ----
  {
    f32x4 ba = *(const f32x4*)(cb1 + oa + hi * 4);
    f32x4 bg = *(const f32x4*)(cb1 + og + hi * 4);
    #pragma unroll
    for (int n = 0; n < 8; n++) {
      int u = n * 16 + lo;
      s16x4 pk;
      #pragma unroll
      for (int j = 0; j < 4; j++)
        pk[j] = (short)f2bf(gate_fn(A[0][n][j] + ba[j], A[1][n][j] + bg[j]));
      *(s16x4*)((char*)zh + u * 256 + (((oa + hi * 4) * 2) ^ ((lo & 7) << 4))) = pk;
    }
  }
  __syncthreads();

  // ---- so1 GEMM ----
  const int ro = wv * 32;
  if (wv < 4) {
    #pragma unroll
    for (int m = 0; m < 2; m++)
      #pragma unroll
      for (int nn = 0; nn < 4; nn++) A[m][nn + 4] = (f32x4){0.f, 0.f, 0.f, 0.f};
    #pragma unroll
    for (int s = 0; s < 4; s++) {
      s16x8 af0 = *(const s16x8*)(ws1 + (size_t)(ro + lo) * 128 + s * 32 + hi * 8);
      s16x8 af1 = *(const s16x8*)(ws1 + (size_t)(ro + 16 + lo) * 128 + s * 32 + hi * 8);
      const int cb_ = s * 64 + hi * 16;
      s16x8 bf[4];
      #pragma unroll
      for (int nn = 0; nn < 4; nn++) {
        int u = (nn + 4) * 16 + lo;
        bf[nn] = *(const s16x8*)((const char*)zh + u * 256 + (cb_ ^ ((lo & 7) << 4)));
      }
      #pragma unroll
      for (int nn = 0; nn < 4; nn++) {
        A[0][nn + 4] = __builtin_amdgcn_mfma_f32_16x16x32_bf16(af0, bf[nn], A[0][nn + 4], 0, 0, 0);
        A[1][nn + 4] = __builtin_amdgcn_mfma_f32_16x16x32_bf16(af1, bf[nn], A[1][nn + 4], 0, 0, 0);
      }
    }
  } else {
    #pragma unroll
    for (int m = 0; m < 2; m++)
      #pragma unroll
      for (int n = 0; n < 8; n++) A[m][n] = (f32x4){0.f, 0.f, 0.f, 0.f};
    #pragma unroll
    for (int s = 0; s < 4; s++) {
      s16x8 af0 = *(const s16x8*)(ws1 + (size_t)(ro + lo) * 128 + s * 32 + hi * 8);
      s16x8 af1 = *(const s16x8*)(ws1 + (size_t)(ro + 16 + lo) * 128 + s * 32 + hi * 8);
      const int cb_ = s * 64 + hi * 16;
      #pragma unroll
      for (int h2 = 0; h2 < 2; h2++) {
        s16x8 bf[4];
        #pragma unroll
        for (int nn = 0; nn < 4; nn++) {
          int u = (h2 * 4 + nn) * 16 + lo;
          bf[nn] = *(const s16x8*)((const char*)zh + u * 256 + (cb_ ^ ((lo & 7) << 4)));
        }
        #pragma unroll
        for (int nn = 0; nn < 4; nn++) {
          A[0][h2 * 4 + nn] = __builtin_amdgcn_mfma_f32_16x16x32_bf16(af0, bf[nn], A[0][h2 * 4 + nn], 0, 0, 0);
          A[1][h2 * 4 + nn] = __builtin_amdgcn_mfma_f32_16x16x32_bf16(af1, bf[nn], A[1][h2 * 4 + nn], 0, 0, 0);
        }
      }
    }
    // epilogue: h1 = (so1 + ob1 + h0)*SH; pack -> h_s rows [0,128)
    #pragma unroll
    for (int m = 0; m < 2; m++) {
      int c0 = (wv - 4) * 32 + m * 16 + hi * 4;
      f32x4 ob4 = *(const f32x4*)(ob1 + c0);
      #pragma unroll
      for (int n = 0; n < 8; n++) {
        int u = n * 16 + lo;
        int t_out = t0 - 64 + u;
        f32x4 h0 = (f32x4){0.f, 0.f, 0.f, 0.f};
        if (t_out >= 0) h0 = *(const f32x4*)(hf_in + ((size_t)b * T + t_out) * 128 + c0);
        f32x4 h1 = (A[m][n] + ob4 + h0) * SH;
        if (t_out < 0) h1 = (f32x4){0.f, 0.f, 0.f, 0.f};
        A[m][n] = h1;
        s16x4 pk;
        #pragma unroll
        for (int j = 0; j < 4; j++) pk[j] = (short)f2bf(h1[j]);
        *(s16x4*)((char*)h_s + u * 256 + ((c0 * 2) ^ ((lo & 7) << 4))) = pk;
      }
    }
  }
  __syncthreads();

  // ---- conv2 GEMM: N=64 own cols ----
  #pragma unroll
  for (int m = 0; m < 2; m++)
    #pragma unroll
    for (int n = 0; n < 4; n++) A[m][n] = (f32x4){0.f, 0.f, 0.f, 0.f};
  #pragma unroll
  for (int k = 0; k < 3; k++) {
    const int st = ((lo + (k + 6) * d2) & 7) << 4;
    const int jb2 = 64 - 2 * d2 + k * d2;
    #pragma unroll
    for (int s = 0; s < 4; s++) {
      s16x8 af0 = *(const s16x8*)(wc2 + ((size_t)(k * 256 + oa + lo)) * 128 + s * 32 + hi * 8);
      s16x8 af1 = *(const s16x8*)(wc2 + ((size_t)(k * 256 + og + lo)) * 128 + s * 32 + hi * 8);
      const int cb_ = s * 64 + hi * 16;
      s16x8 bf[4];
      #pragma unroll
      for (int nn = 0; nn < 4; nn++) {
        int j1 = nn * 16 + lo + jb2;
        bf[nn] = *(const s16x8*)((const char*)h_s + j1 * 256 + (cb_ ^ st));
      }
      #pragma unroll
      for (int nn = 0; nn < 4; nn++) {
        A[0][nn] = __builtin_amdgcn_mfma_f32_16x16x32_bf16(af0, bf[nn], A[0][nn], 0, 0, 0);
        A[1][nn] = __builtin_amdgcn_mfma_f32_16x16x32_bf16(af1, bf[nn], A[1][nn], 0, 0, 0);
      }
    }
  }
  // ---- gate2 -> zh rows [0,64) ----
  {
    f32x4 ba = *(const f32x4*)(cb2 + oa + hi * 4);
    f32x4 bg = *(const f32x4*)(cb2 + og + hi * 4);
    #pragma unroll
    for (int n = 0; n < 4; n++) {
      int u = n * 16 + lo;
      s16x4 pk;
      #pragma unroll
      for (int j = 0; j < 4; j++)
        pk[j] = (short)f2bf(gate_fn(A[0][n][j] + ba[j], A[1][n][j] + bg[j]));
      *(s16x4*)((char*)zh + u * 256 + (((oa + hi * 4) * 2) ^ ((lo & 7) << 4))) = pk;
    }
  }
  __syncthreads();

  // ---- so2 GEMM: N=64 ----
  if (wv < 4) {
    #pragma unroll
    for (int s = 0; s < 4; s++) {
      s16x8 af0 = *(const s16x8*)(ws2 + (size_t)(ro + lo) * 128 + s * 32 + hi * 8);
      s16x8 af1 = *(const s16x8*)(ws2 + (size_t)(ro + 16 + lo) * 128 + s * 32 + hi * 8);
      const int cb_ = s * 64 + hi * 16;
      s16x8 bf[4];
      #pragma unroll
      for (int nn = 0; nn < 4; nn++) {
        int u = nn * 16 + lo;
        bf[nn] = *(const s16x8*)((const char*)zh + u * 256 + (cb_ ^ ((lo & 7) << 4)));
      }
      #pragma unroll
      for (int nn = 0; nn < 4; nn++) {
        A[0][nn + 4] = __builtin_amdgcn_mfma_f32_16x16x32_bf16(af0, bf[nn], A[0][nn + 4], 0, 0, 0);
        A[1][nn + 4] = __builtin_amdgcn_mfma_f32_16x16x32_bf16(af1, bf[nn], A[1][nn + 4], 0, 0, 0);
      }
    }
    #pragma unroll
    for (int m = 0; m < 2; m++) {
      int c0 = ro + m * 16 + hi * 4;
      #pragma unroll
      for (int n = 0; n < 4; n++) {
        int t = t0 + n * 16 + lo;
        size_t off = ((size_t)b * T + t) * 128 + c0;
        f32x4 r = A[m][n + 4];
        if (!first) r += *(const f32x4*)(skip + off);
        *(f32x4*)(skip + off) = r;
      }
    }
  } else {
    #pragma unroll
    for (int m = 0; m < 2; m++)
      #pragma unroll
      for (int n = 0; n < 4; n++) A[m][n] = (f32x4){0.f, 0.f, 0.f, 0.f};
    #pragma unroll
    for (int s = 0; s < 4; s++) {
      s16x8 af0 = *(const s16x8*)(ws2 + (size_t)(ro + lo) * 128 + s * 32 + hi * 8);
      s16x8 af1 = *(const s16x8*)(ws2 + (size_t)(ro + 16 + lo) * 128 + s * 32 + hi * 8);
      const int cb_ = s * 64 + hi * 16;
      s16x8 bf[4];
      #pragma unroll
      for (int nn = 0; nn < 4; nn++) {
        int u = nn * 16 + lo;
        bf[nn] = *(const s16x8*)((const char*)zh + u * 256 + (cb_ ^ ((lo & 7) << 4)));
      }
      #pragma unroll
      for (int nn = 0; nn < 4; nn++) {
        A[0][nn] = __builtin_amdgcn_mfma_f32_16x16x32_bf16(af0, bf[nn], A[0][nn], 0, 0, 0);
        A[1][nn] = __builtin_amdgcn_mfma_f32_16x16x32_bf16(af1, bf[nn], A[1][nn], 0, 0, 0);
      }
    }
    #pragma unroll
    for (int m = 0; m < 2; m++) {
      int c0 = (wv - 4) * 32 + m * 16 + hi * 4;
      f32x4 ob4 = *(const f32x4*)(ob2 + c0);
      #pragma unroll
      for (int n = 0; n < 4; n++) {
        int t = t0 + n * 16 + lo;
        f32x4 h2v = (A[m][n] + ob4 + A[m][n + 4]) * SH;
        *(f32x4*)(hf_out + ((size_t)b * T + t) * 128 + c0) = h2v;
        // shadow write (pre-swizzled): key = (t&7)<<3 = (lo&7)<<3
        s16x4 pk;
        #pragma unroll
        for (int j = 0; j < 4; j++) pk[j] = (short)f2bf(h2v[j]);
        *(s16x4*)(sh_out + ((size_t)b * T + t) * 128 + (c0 ^ ((lo & 7) << 3))) = pk;
      }
    }
  }
}

// ---------------- fused head ----------------
__global__ __launch_bounds__(256, 2)
void head_kernel(const float* __restrict__ skip, const float* __restrict__ sumsb,
                 const u16* __restrict__ w1, const float* __restrict__ b1v,
                 const u16* __restrict__ w2, const float* __restrict__ b2v,
                 float* __restrict__ out) {
  __shared__ u16 sT[64 * 128];
  __shared__ u16 s1T[64 * 128];
  const int tid = threadIdx.x, wv = tid >> 6, lane = tid & 63, lo = lane & 15, hi = lane >> 4;
  const int t0 = blockIdx.x * 64, b = blockIdx.y;

  #pragma unroll
  for (int it = 0; it < 8; it++) {
    int p = tid + it * 256;
    int t = p >> 5, cq = p & 31;
    f32x4 v = *(const f32x4*)(skip + ((size_t)b * T + t0 + t) * 128 + cq * 4);
    f32x4 sb4 = *(const f32x4*)(sumsb + cq * 4);
    s16x4 pk;
    #pragma unroll
    for (int j = 0; j < 4; j++) pk[j] = (short)f2bf(fmaxf((v[j] + sb4[j]) * SKIP_SCALE, 0.f));
    *(s16x4*)((char*)sT + t * 256 + ((cq * 8) ^ ((t & 7) << 4))) = pk;
  }
  __syncthreads();
  {
    f32x4 acc[2][4];
    #pragma unroll
    for (int m = 0; m < 2; m++)
      #pragma unroll
      for (int n = 0; n < 4; n++) acc[m][n] = (f32x4){0.f, 0.f, 0.f, 0.f};
    #pragma unroll
    for (int s = 0; s < 4; s++) {
      s16x8 af0 = *(const s16x8*)(w1 + (size_t)(wv * 32 + lo) * 128 + s * 32 + hi * 8);
      s16x8 af1 = *(const s16x8*)(w1 + (size_t)(wv * 32 + 16 + lo) * 128 + s * 32 + hi * 8);
      #pragma unroll
      for (int n = 0; n < 4; n++) {
        int t = n * 16 + lo;
        s16x8 bf = *(const s16x8*)((const char*)sT + t * 256 + ((s * 64 + hi * 16) ^ ((t & 7) << 4)));
        acc[0][n] = __builtin_amdgcn_mfma_f32_16x16x32_bf16(af0, bf, acc[0][n], 0, 0, 0);
        acc[1][n] = __builtin_amdgcn_mfma_f32_16x16x32_bf16(af1, bf, acc[1][n], 0, 0, 0);
      }
    }
    #pragma unroll
    for (int m = 0; m < 2; m++) {
      int c0 = wv * 32 + m * 16 + hi * 4;
      f32x4 bv = *(const f32x4*)(b1v + c0);
      #pragma unroll
      for (int n = 0; n < 4; n++) {
        int t = n * 16 + lo;
        s16x4 pk;
        #pragma unroll
        for (int j = 0; j < 4; j++) pk[j] = (short)f2bf(fmaxf(acc[m][n][j] + bv[j], 0.f));
        *(s16x4*)((char*)s1T + t * 256 + ((c0 * 2) ^ ((t & 7) << 4))) = pk;
      }
    }
  }
  __syncthreads();
  {
    f32x4 acc[4][4];
    #pragma unroll
    for (int m = 0; m < 4; m++)
      #pragma unroll
      for (int n = 0; n < 4; n++) acc[m][n] = (f32x4){0.f, 0.f, 0.f, 0.f};
    #pragma unroll
    for (int s = 0; s < 4; s++) {
      s16x8 af[4];
      #pragma unroll
      for (int m = 0; m < 4; m++)
        af[m] = *(const s16x8*)(w2 + (size_t)(wv * 64 + m * 16 + lo) * 128 + s * 32 + hi * 8);
      #pragma unroll
      for (int n = 0; n < 4; n++) {
        int t = n * 16 + lo;
        s16x8 bf = *(const s16x8*)((const char*)s1T + t * 256 + ((s * 64 + hi * 16) ^ ((t & 7) << 4)));
        #pragma unroll
        for (int m = 0; m < 4; m++)
          acc[m][n] = __builtin_amdgcn_mfma_f32_16x16x32_bf16(af[m], bf, acc[m][n], 0, 0, 0);
      }
    }
    #pragma unroll
    for (int m = 0; m < 4; m++) {
      int c0 = wv * 64 + m * 16 + hi * 4;
      f32x4 bv = *(const f32x4*)(b2v + c0);
      #pragma unroll
      for (int n = 0; n < 4; n++) {
        int t = t0 + n * 16 + lo;
        f32x4 r = acc[m][n] + bv;
        #pragma unroll
        for (int j = 0; j < 4; j++) out[((size_t)b * CIN + c0 + j) * T + t] = r[j];
      }
    }
  }
}

// ---------------------------------------------------------------------------
extern "C" void kernel_launch(void* const* d_in, const int* in_sizes, int n_in,
                              void* d_out, int out_size, void* d_ws, size_t ws_size,
                              hipStream_t stream) {
  const float* x       = (const float*)d_in[0];
  const float* first_w = (const float*)d_in[1];
  const float* first_b = (const float*)d_in[2];
  const float* conv_w  = (const float*)d_in[3];
  const float* conv_b  = (const float*)d_in[4];
  const float* out_w   = (const float*)d_in[5];
  const float* out_b   = (const float*)d_in[6];
  const float* skip_w  = (const float*)d_in[7];
  const float* skip_b  = (const float*)d_in[8];
  const float* last1_w = (const float*)d_in[9];
  const float* last1_b = (const float*)d_in[10];
  const float* last2_w = (const float*)d_in[11];
  const float* last2_b = (const float*)d_in[12];
  float* outp = (float*)d_out;

  const size_t NBT = (size_t)B * T * 128;        // 4,194,304 elements
  u16* wcv = (u16*)d_ws;                         // 2,359,296 u16
  u16* wso = wcv + (size_t)NL * 3 * 256 * 128;   // 786,432
  u16* wfB = wso + (size_t)NL * 256 * 128;       // 32,768
  u16* w1B = wfB + 128 * 256;                    // 16,384
  u16* w2B = w1B + 128 * 128;                    // 32,768
  float* sumsb = (float*)(w2B + 256 * 128);      // 128 f32
  float* skipF = sumsb + 128;                    // 16MB fp32 skip accumulator
  u16* shA = (u16*)(skipF + NBT);                // bf16 shadow A (+1024 slack)
  u16* shB = shA + NBT + 1024;                   // bf16 shadow B (+1024 slack)
  float* hfA = (float*)d_out;                    // fp32 residual double-buffer in d_out
  float* hfB = hfA + NBT;

  cvt_all<<<12608, 256, 0, stream>>>(conv_w, skip_w, out_w, first_w, last1_w, last2_w,
                                     wcv, wso, wfB, w1B, w2B);
  sumsb_kernel<<<1, 128, 0, stream>>>(skip_b, sumsb);

  dim3 g64(T / 64, B);
  first_kernel<<<g64, 256, 0, stream>>>(x, wfB, first_b, hfA, shA);

  for (int p = 0; p < NL / 2; p++) {
    int l1 = 2 * p, l2 = 2 * p + 1;
    int d1 = 1 << (l1 % 6), d2 = 1 << (l2 % 6);
    const float* hin = (p & 1) ? hfB : hfA;
    float* hout = (p & 1) ? hfA : hfB;
    const u16* shin = (p & 1) ? shB : shA;
    u16* shout = (p & 1) ? shA : shB;
    pair_kernel<<<g64, 512, 73728, stream>>>(
        hin, hout, shin, shout, skipF,
        wcv + (size_t)l1 * 3 * 256 * 128, conv_b + (size_t)l1 * 256,
        wso + (size_t)l1 * 256 * 128, out_b + (size_t)l1 * 128,
        wcv + (size_t)l2 * 3 * 256 * 128, conv_b + (size_t)l2 * 256,
        wso + (size_t)l2 * 256 * 128, out_b + (size_t)l2 * 128,
        d1, d2, p == 0 ? 1 : 0);
  }
  head_kernel<<<g64, 256, 0, stream>>>(skipF, sumsb, w1B, last1_b, w2B, last2_b, outp);
}